// Round 11
// baseline (274.475 us; speedup 1.0000x reference)
//
#include <hip/hip_runtime.h>
#include <cstdint>
#include <cstddef>

typedef __bf16 bf16;
typedef __attribute__((ext_vector_type(8))) __bf16 bf16x8;
typedef __attribute__((ext_vector_type(4))) __bf16 bf16x4;
typedef __attribute__((ext_vector_type(4))) float f32x4;

#define ADIM 1024
#define ASEQ 2048
#define ABATCH 8

__device__ __forceinline__ void gload_lds16(const void* g, void* l) {
  __builtin_amdgcn_global_load_lds(
      (const __attribute__((address_space(1))) void*)g,
      (__attribute__((address_space(3))) void*)l,
      16, 0, 0);
}

__device__ __forceinline__ f32x4 mfma16(bf16x8 a, bf16x8 b, f32x4 c) {
  return __builtin_amdgcn_mfma_f32_16x16x32_bf16(a, b, c, 0, 0, 0);
}

// ------- merged prep: cast x (blocks 0..2047) + transpose weights (2048..3071) -------
__global__ __launch_bounds__(256) void k_prep(
    const float* __restrict__ x, bf16* __restrict__ xb, int n4,
    const float* __restrict__ Wq, const float* __restrict__ Wk,
    const float* __restrict__ Wv, const float* __restrict__ Wo,
    bf16* __restrict__ WcT, bf16* __restrict__ WoT) {
  if (blockIdx.x < 2048) {
    int i = blockIdx.x * blockDim.x + threadIdx.x;
    int stride = 2048 * blockDim.x;
    for (; i < n4; i += stride) {
      float4 f = ((const float4*)x)[i];
      bf16x4 o = { (bf16)f.x, (bf16)f.y, (bf16)f.z, (bf16)f.w };
      ((bf16x4*)xb)[i] = o;
    }
    return;
  }
  const int b = blockIdx.x - 2048;
  const int which = b >> 8, t = b & 255;
  const int n0 = (t & 15) * 64, k0 = (t >> 4) * 64;
  const float* W = (which == 0) ? Wq : (which == 1) ? Wk : (which == 2) ? Wv : Wo;
  bf16* out = (which < 3) ? (WcT + (size_t)which * ADIM * ADIM) : WoT;

  __shared__ float tile[64][69];
  const int r = threadIdx.x >> 4, c4 = (threadIdx.x & 15) * 4;
#pragma unroll
  for (int p = 0; p < 4; ++p) {
    float4 f = *(const float4*)&W[(size_t)(k0 + p * 16 + r) * ADIM + n0 + c4];
    tile[p * 16 + r][c4 + 0] = f.x;
    tile[p * 16 + r][c4 + 1] = f.y;
    tile[p * 16 + r][c4 + 2] = f.z;
    tile[p * 16 + r][c4 + 3] = f.w;
  }
  __syncthreads();
#pragma unroll
  for (int p = 0; p < 4; ++p) {
    const int nn = p * 16 + r;
    bf16x4 o;
#pragma unroll
    for (int j = 0; j < 4; ++j) o[j] = (bf16)tile[c4 + j][nn];
    *(bf16x4*)&out[(size_t)(n0 + nn) * ADIM + k0 + c4] = o;
  }
}

// ==== 256x256 BK=64 GEMM: A via gload_lds dbuf; B DIRECT global->registers ====
// Rationale (r10 post-mortem): all schedules plateau at staging-path rate
// ~6.3 TB/s; halve staged DMA bytes by never putting B in LDS. Each lane's
// B-fragment is 16 contiguous bytes of BT (same elements the LDS path read):
//   lane l, tile j, ks: BT[(n0+wn*64+j*16+(l&15))*K + t*64 + ks*32 + (l>>4)*8]
// B is L2-hot (<=6 MB). ks0 frags for t+1 prefetched during t (bnx carry,
// 16 VGPR); ks1 frags loaded intra-step, latency hidden under ks0 MFMAs.
// All loads compiler-visible (it inserts vmcnt for reg deps); only the
// end-of-step vmcnt(0)+s_barrier (r8-proven) is hand-written.
// LDS: A only, 2 x 32 KiB. Swizzle on A unchanged from r8 (conflict-free).
// MODE 0: fused QKV epilogue; MODE 1: fp32 out + bias.
template<int MODE>
__global__ __launch_bounds__(512, 2) void k_gbd(
    const bf16* __restrict__ A, const bf16* __restrict__ BT,
    const float* __restrict__ bias0, const float* __restrict__ bias1,
    const float* __restrict__ bias2,
    bf16* __restrict__ Qo, bf16* __restrict__ Ko, bf16* __restrict__ Vto,
    float* __restrict__ outF, int ntn)
{
  constexpr int K = 1024;
  constexpr int KT = K / 64;   // 16 steps of BK=64
  const int nwg = gridDim.x;
  const int cpx = nwg >> 3;
  const int flat = blockIdx.x;
  const int sw = (flat & 7) * cpx + (flat >> 3);   // grid % 8 == 0 (bijective)
  const int bx = sw % ntn, by = sw / ntn;
  const int m0 = by * 256, n0 = bx * 256;

  const int tid = threadIdx.x;
  const int l = tid & 63, w = tid >> 6;
  const int wm = w >> 2, wn = w & 3;     // 2M x 4N
  const int lr = l & 15, kg = l >> 4;    // kg in 0..3

  __shared__ alignas(16) bf16 sA[2][256 * 64];   // 64 KiB total

  f32x4 acc[8][4] = {};

  // A ds_read byte offsets for ks=0 (ks=1: offset ^ 64), swizzled (r8 layout)
  int oA[8];
#pragma unroll
  for (int i = 0; i < 8; ++i) {
    int r = wm * 128 + i * 16 + lr;
    oA[i] = (r * 8 + (kg ^ (r & 7))) * 16;
  }

  // B per-lane base: row n0+wn*64+lr, k-offset kg*8; j adds 16*K, ks adds 32, t adds 64
  const bf16* bp = BT + (size_t)(n0 + wn * 64 + lr) * K + kg * 8;

  auto stA = [&](int c, int kt, int chunk) {
    int s = chunk * 512 + tid;                    // linear 16B slot
    int prow = s >> 3, ps = s & 7;
    int lc = ps ^ (prow & 7);                     // inverse swizzle on source
    gload_lds16(A + (size_t)(m0 + prow) * K + kt * 64 + lc * 8,
                &sA[c][(size_t)s * 8]);
  };

  bf16x8 bcu[4], bnx[4], b1r[4];

  // prologue: A(0) into buf 0; B ks0 frags of tile 0
#pragma unroll
  for (int ch = 0; ch < 4; ++ch) stA(0, 0, ch);
#pragma unroll
  for (int j = 0; j < 4; ++j)
    bcu[j] = *(const bf16x8*)(bp + (size_t)j * 16 * K);
  asm volatile("s_waitcnt vmcnt(0)\n\ts_barrier" ::: "memory");

  for (int t = 0; t < KT; ++t) {
    const int c = t & 1;
    const char* bA = (const char*)&sA[c][0];
    const bf16* bpt = bp + t * 64;

    // issue B ks1 loads (tile t) early — consumed by the second MFMA cluster
#pragma unroll
    for (int j = 0; j < 4; ++j)
      b1r[j] = *(const bf16x8*)(bpt + (size_t)j * 16 * K + 32);

    bf16x8 af[8];
#pragma unroll
    for (int i = 0; i < 8; ++i) af[i] = *(const bf16x8*)(bA + oA[i]);

    if (t + 1 < KT) {
#pragma unroll
      for (int ch = 0; ch < 4; ++ch) stA(c ^ 1, t + 1, ch);
#pragma unroll
      for (int j = 0; j < 4; ++j)
        bnx[j] = *(const bf16x8*)(bpt + (size_t)j * 16 * K + 64);
    }

    __builtin_amdgcn_s_setprio(1);
#pragma unroll
    for (int i = 0; i < 8; ++i)
#pragma unroll
      for (int j = 0; j < 4; ++j)
        acc[i][j] = mfma16(af[i], bcu[j], acc[i][j]);
    __builtin_amdgcn_s_setprio(0);

    // ks=1 half
#pragma unroll
    for (int i = 0; i < 8; ++i) af[i] = *(const bf16x8*)(bA + (oA[i] ^ 64));

    __builtin_amdgcn_s_setprio(1);
#pragma unroll
    for (int i = 0; i < 8; ++i)
#pragma unroll
      for (int j = 0; j < 4; ++j)
        acc[i][j] = mfma16(af[i], b1r[j], acc[i][j]);
    __builtin_amdgcn_s_setprio(0);

    if (t + 1 < KT) {
#pragma unroll
      for (int j = 0; j < 4; ++j) bcu[j] = bnx[j];
    }

    asm volatile("s_waitcnt vmcnt(0)\n\ts_barrier" ::: "memory");
  }

  // ---- epilogue ----
  const int cb = n0 >> 10;          // uniform per block (256 | 1024)
#pragma unroll
  for (int i = 0; i < 8; ++i) {
#pragma unroll
    for (int jj = 0; jj < 4; ++jj) {
      const int n = n0 + wn * 64 + jj * 16 + lr;
      const int m0r = m0 + wm * 128 + i * 16 + kg * 4;
      if (MODE == 0) {
        const int nn = n & 1023;
        if (cb == 0) {
          const float b_ = bias0[nn];
#pragma unroll
          for (int r = 0; r < 4; ++r)
            Qo[(size_t)(m0r + r) * ADIM + nn] = (bf16)(acc[i][jj][r] + b_);
        } else if (cb == 1) {
          const float b_ = bias1[nn];
#pragma unroll
          for (int r = 0; r < 4; ++r) {
            float v = acc[i][jj][r] + b_;
            Ko[(size_t)(m0r + r) * ADIM + nn] = (bf16)(v > 0.f ? v + 1.f : __expf(v));
          }
        } else {
          const float b_ = bias2[nn];
          const int bb = m0r >> 11, t0c = m0r & 2047;
          bf16x4 pk;
#pragma unroll
          for (int r = 0; r < 4; ++r) pk[r] = (bf16)(acc[i][jj][r] + b_);
          *(bf16x4*)&Vto[((size_t)bb * ADIM + nn) * ASEQ + t0c] = pk;
        }
      } else {
        const float b_ = bias0[n];
#pragma unroll
        for (int r = 0; r < 4; ++r)
          outF[(size_t)(m0r + r) * ADIM + n] = acc[i][jj][r] + b_;
      }
    }
  }
}

// --------- windowed decay attention: one (batch, 64-row q-tile) per WG ---------
__global__ __launch_bounds__(256) void k_attn(
    const bf16* __restrict__ Qg, const bf16* __restrict__ Kg,
    const bf16* __restrict__ Vt, bf16* __restrict__ Rb,
    const float* __restrict__ decay_param)
{
  const int b = blockIdx.y;
  const int T0 = blockIdx.x * 64;
  const int tid = threadIdx.x;
  const int l = tid & 63, w = tid >> 6;
  const int lr = l & 15, lk = (l >> 4) * 8;

  const float dp = decay_param[0];
  const float decay = 1.f / (1.f + __expf(-dp));
  const float l2d = __log2f(decay);

  __shared__ alignas(16) bf16 lQ[2][64 * 32];
  __shared__ alignas(16) bf16 lK[2][128 * 32];
  __shared__ alignas(16) bf16 lV[2][128 * 32];
  __shared__ alignas(16) bf16 lP[64 * 136];

  const bf16* Qb = Qg + (size_t)(b * ASEQ + T0) * ADIM;

  auto stageQK = [&](int buf, int k0) {
    {
      const bf16* g = Qb + (size_t)(w * 16 + (l >> 2)) * ADIM + k0 + (l & 3) * 8;
      gload_lds16(g, &lQ[buf][w * 16 * 32]);
    }
#pragma unroll
    for (int cc = 0; cc < 2; ++cc) {
      int c = 2 * w + cc;
      int sg = T0 - 64 + c * 16 + (l >> 2);
      if (sg < 0) sg = 0;
      const bf16* g = Kg + (size_t)(b * ASEQ + sg) * ADIM + k0 + (l & 3) * 8;
      gload_lds16(g, &lK[buf][c * 16 * 32]);
    }
  };

  f32x4 sc[4][2] = {};
  stageQK(0, 0);
  __syncthreads();
  for (int kt = 0; kt < 32; ++kt) {
    int cur = kt & 1;
    if (kt + 1 < 32) stageQK(cur ^ 1, (kt + 1) * 32);
    bf16x8 af[4], bfr[2];
#pragma unroll
    for (int i = 0; i < 4; ++i)
      af[i] = *(const bf16x8*)&lQ[cur][(i * 16 + lr) * 32 + lk];
#pragma unroll
    for (int j = 0; j < 2; ++j)
      bfr[j] = *(const bf16x8*)&lK[cur][(w * 32 + j * 16 + lr) * 32 + lk];
#pragma unroll
    for (int i = 0; i < 4; ++i)
#pragma unroll
      for (int j = 0; j < 2; ++j)
        sc[i][j] = mfma16(af[i], bfr[j], sc[i][j]);
    __syncthreads();
  }

  const int er = (l >> 4) * 4, ec = l & 15;
#pragma unroll
  for (int i = 0; i < 4; ++i)
#pragma unroll
    for (int j = 0; j < 2; ++j)
#pragma unroll
      for (int r = 0; r < 4; ++r) {
        int tl = i * 16 + er + r;
        int sl = w * 32 + j * 16 + ec;
        int sg = T0 - 64 + sl;
        int delta = (T0 + tl) - 1 - sg;
        float wgt = (delta >= 0 && delta < 64 && sg >= 0)
                        ? exp2f((float)delta * l2d) : 0.f;
        lP[tl * 136 + sl] = (bf16)(sc[i][j][r] * wgt);
      }

  auto stageV = [&](int buf, int g) {
    int nc = g >> 2, ks = g & 3;
#pragma unroll
    for (int cc = 0; cc < 2; ++cc) {
      int c = 2 * w + cc;
      int drow = nc * 128 + c * 16 + (l >> 2);
      int scol = T0 - 64 + ks * 32 + (l & 3) * 8;
      if (scol < 0) scol = 0;
      const bf16* gv = Vt + ((size_t)b * ADIM + drow) * ASEQ + scol;
      gload_lds16(gv, &lV[buf][c * 16 * 32]);
    }
  };

  f32x4 o[4][2] = {};
  stageV(0, 0);
  __syncthreads();

  for (int g = 0; g < 32; ++g) {
    int cur = g & 1;
    if (g + 1 < 32) stageV(cur ^ 1, g + 1);
    int nc = g >> 2, ks = g & 3;
    bf16x8 af[4], bfr[2];
#pragma unroll
    for (int i = 0; i < 4; ++i)
      af[i] = *(const bf16x8*)&lP[(i * 16 + lr) * 136 + ks * 32 + lk];
#pragma unroll
    for (int j = 0; j < 2; ++j)
      bfr[j] = *(const bf16x8*)&lV[cur][(w * 32 + j * 16 + lr) * 32 + lk];
#pragma unroll
    for (int i = 0; i < 4; ++i)
#pragma unroll
      for (int j = 0; j < 2; ++j)
        o[i][j] = mfma16(af[i], bfr[j], o[i][j]);
    if (ks == 3) {
#pragma unroll
      for (int i = 0; i < 4; ++i)
#pragma unroll
        for (int j = 0; j < 2; ++j) {
#pragma unroll
          for (int r = 0; r < 4; ++r) {
            int tl = i * 16 + er + r;
            int dl = nc * 128 + w * 32 + j * 16 + ec;
            Rb[(size_t)(b * ASEQ + T0 + tl) * ADIM + dl] = (bf16)o[i][j][r];
          }
#pragma unroll
          for (int r = 0; r < 4; ++r) o[i][j][r] = 0.f;
        }
    }
    __syncthreads();
  }
}

extern "C" void kernel_launch(void* const* d_in, const int* in_sizes, int n_in,
                              void* d_out, int out_size, void* d_ws, size_t ws_size,
                              hipStream_t stream) {
  const float* x  = (const float*)d_in[0];
  const float* Wq = (const float*)d_in[1];
  const float* bq = (const float*)d_in[2];
  const float* Wk = (const float*)d_in[3];
  const float* bk = (const float*)d_in[4];
  const float* Wv = (const float*)d_in[5];
  const float* bv = (const float*)d_in[6];
  const float* Wo = (const float*)d_in[7];
  const float* bo = (const float*)d_in[8];
  const float* dp = (const float*)d_in[9];
  float* out = (float*)d_out;

  char* ws = (char*)d_ws;
  bf16* Xb  = (bf16*)(ws + ((size_t)0 << 20));    // [16384][1024]
  bf16* Qb  = (bf16*)(ws + ((size_t)32 << 20));
  bf16* Kb  = (bf16*)(ws + ((size_t)64 << 20));
  bf16* Vtb = (bf16*)(ws + ((size_t)96 << 20));   // [8][1024][2048]
  bf16* Rbb = (bf16*)(ws + ((size_t)128 << 20));
  bf16* WcT = (bf16*)(ws + ((size_t)160 << 20));  // [3072][1024]
  bf16* WoT = (bf16*)(ws + ((size_t)166 << 20));  // [1024][1024]

  const int M = ABATCH * ASEQ;  // 16384

  k_prep<<<3072, 256, 0, stream>>>(x, Xb, (M * ADIM) / 4,
                                   Wq, Wk, Wv, Wo, WcT, WoT);
  k_gbd<0><<<768, 512, 0, stream>>>(
      Xb, WcT, bq, bk, bv, Qb, Kb, Vtb, nullptr, 12);
  k_attn<<<dim3(32, 8), 256, 0, stream>>>(Qb, Kb, Vtb, Rbb, dp);
  k_gbd<1><<<256, 512, 0, stream>>>(
      Rbb, WoT, bo, nullptr, nullptr, nullptr, nullptr, nullptr, out, 4);
}

// Round 12
// 215.317 us; speedup vs baseline: 1.2747x; 1.2747x over previous
//
#include <hip/hip_runtime.h>
#include <cstdint>
#include <cstddef>

typedef __bf16 bf16;
typedef __attribute__((ext_vector_type(8))) __bf16 bf16x8;
typedef __attribute__((ext_vector_type(4))) __bf16 bf16x4;
typedef __attribute__((ext_vector_type(4))) float f32x4;

#define ADIM 1024
#define ASEQ 2048
#define ABATCH 8

__device__ __forceinline__ void gload_lds16(const void* g, void* l) {
  __builtin_amdgcn_global_load_lds(
      (const __attribute__((address_space(1))) void*)g,
      (__attribute__((address_space(3))) void*)l,
      16, 0, 0);
}

__device__ __forceinline__ f32x4 mfma16(bf16x8 a, bf16x8 b, f32x4 c) {
  return __builtin_amdgcn_mfma_f32_16x16x32_bf16(a, b, c, 0, 0, 0);
}

// ------- merged prep: cast x (blocks 0..2047) + transpose weights (2048..3071) -------
__global__ __launch_bounds__(256) void k_prep(
    const float* __restrict__ x, bf16* __restrict__ xb, int n4,
    const float* __restrict__ Wq, const float* __restrict__ Wk,
    const float* __restrict__ Wv, const float* __restrict__ Wo,
    bf16* __restrict__ WcT, bf16* __restrict__ WoT) {
  if (blockIdx.x < 2048) {
    int i = blockIdx.x * blockDim.x + threadIdx.x;
    int stride = 2048 * blockDim.x;
    for (; i < n4; i += stride) {
      float4 f = ((const float4*)x)[i];
      bf16x4 o = { (bf16)f.x, (bf16)f.y, (bf16)f.z, (bf16)f.w };
      ((bf16x4*)xb)[i] = o;
    }
    return;
  }
  const int b = blockIdx.x - 2048;
  const int which = b >> 8, t = b & 255;
  const int n0 = (t & 15) * 64, k0 = (t >> 4) * 64;
  const float* W = (which == 0) ? Wq : (which == 1) ? Wk : (which == 2) ? Wv : Wo;
  bf16* out = (which < 3) ? (WcT + (size_t)which * ADIM * ADIM) : WoT;

  __shared__ float tile[64][69];
  const int r = threadIdx.x >> 4, c4 = (threadIdx.x & 15) * 4;
#pragma unroll
  for (int p = 0; p < 4; ++p) {
    float4 f = *(const float4*)&W[(size_t)(k0 + p * 16 + r) * ADIM + n0 + c4];
    tile[p * 16 + r][c4 + 0] = f.x;
    tile[p * 16 + r][c4 + 1] = f.y;
    tile[p * 16 + r][c4 + 2] = f.z;
    tile[p * 16 + r][c4 + 3] = f.w;
  }
  __syncthreads();
#pragma unroll
  for (int p = 0; p < 4; ++p) {
    const int nn = p * 16 + r;
    bf16x4 o;
#pragma unroll
    for (int j = 0; j < 4; ++j) o[j] = (bf16)tile[c4 + j][nn];
    *(bf16x4*)&out[(size_t)(n0 + nn) * ADIM + k0 + c4] = o;
  }
}

// ===== 256x256 BK=64 GEMM — faithful m201 8-phase, 2 tiles/iter, vmcnt(6) =====
// 512 thr = 8 waves (2M x 4N), per-wave C 128x64 (acc[8][4]). LDS 128 KiB:
// s{A,B}[dbuf][half][128*64]. A-half = bit6 of row; B-half = bit5 of col.
// Iter u covers tiles T0=2u (dbuf0), T1=2u+1 (dbuf1). Stage order:
//  p1:Ah1(T1)->d1  p2:Ah0(2u+2)->d0  p3:Bh0(2u+2)->d0  p4:Bh1(2u+2)->d0
//  p5:Ah1(2u+2)->d0  p6:Ah0(2u+3)->d1  p7:Bh0(2u+3)->d1  p8:Bh1(2u+3)->d1
// vmcnt(6) ONLY at p4/p8: at p4, queue=[3 halves of T1(iter u-1 p6-8), Ah1(T1),
//  p2,p3,p4]=14 -> retires 8 = ALL of tile T1 (needed at p5). At p8 retires all
//  of tile 2u+2 (needed at next p1). 3 half-tiles stay in flight; never 0.
// WAR: each staged slot's last ds_read is in a strictly earlier phase; stage
//  issue follows that phase's trailing barrier; reads complete pre-MFMA
//  (lgkmcnt) which precede the barrier => no clobber. Tail iters re-stage the
//  resident tile (identical bytes - benign).
// Phase body: reads; stage; [lgkmcnt(8) if 12 reads]; barrier; lgkmcnt(0);
//  setprio(1); 16 MFMA; setprio(0); barrier.
// Swizzle: 16B slot c16 ^ (hrow&7) (involution), inverse on global source.
template<int MODE>
__global__ __launch_bounds__(512, 2) void k_g8f(
    const bf16* __restrict__ A, const bf16* __restrict__ BT,
    const float* __restrict__ bias0, const float* __restrict__ bias1,
    const float* __restrict__ bias2,
    bf16* __restrict__ Qo, bf16* __restrict__ Ko, bf16* __restrict__ Vto,
    float* __restrict__ outF, int ntn)
{
  constexpr int K = 1024;
  constexpr int KT = 16;
  const int nwg = gridDim.x;
  const int cpx = nwg >> 3;
  const int flat = blockIdx.x;
  const int sw = (flat & 7) * cpx + (flat >> 3);   // grid % 8 == 0 (bijective)
  const int bx = sw % ntn, by = sw / ntn;
  const int m0 = by * 256, n0 = bx * 256;

  const int tid = threadIdx.x;
  const int l = tid & 63, w = tid >> 6;
  const int wm = w >> 2, wn = w & 3;
  const int lr = l & 15, kg = l >> 4;

  __shared__ alignas(16) bf16 sA[2][2][128 * 64];   // [dbuf][half] 64 KiB
  __shared__ alignas(16) bf16 sB[2][2][128 * 64];   // 64 KiB

  f32x4 acc[8][4] = {};

  int oA[4][2], oB[2][2];
#pragma unroll
  for (int i = 0; i < 4; ++i)
#pragma unroll
    for (int ks = 0; ks < 2; ++ks) {
      int hrow = wm * 64 + i * 16 + lr;
      int c16 = ks * 4 + kg;
      oA[i][ks] = (hrow * 8 + (c16 ^ (hrow & 7))) * 16;
    }
#pragma unroll
  for (int j = 0; j < 2; ++j)
#pragma unroll
    for (int ks = 0; ks < 2; ++ks) {
      int hnrow = wn * 32 + j * 16 + lr;
      int c16 = ks * 4 + kg;
      oB[j][ks] = (hnrow * 8 + (c16 ^ (hnrow & 7))) * 16;
    }

  auto stA = [&](int d, int h, int kt) {
#pragma unroll
    for (int c = 0; c < 2; ++c) {
      int s = c * 512 + tid;
      int hrow = s >> 3, ps = s & 7;
      int lc = ps ^ (hrow & 7);
      int r = (hrow & 63) | ((hrow >> 6) << 7) | (h << 6);
      gload_lds16(A + (size_t)(m0 + r) * K + kt * 64 + lc * 8,
                  &sA[d][h][(size_t)s * 8]);
    }
  };
  auto stB = [&](int d, int h, int kt) {
#pragma unroll
    for (int c = 0; c < 2; ++c) {
      int s = c * 512 + tid;
      int hnrow = s >> 3, ps = s & 7;
      int lc = ps ^ (hnrow & 7);
      int n = (hnrow & 31) | ((hnrow >> 5) << 6) | (h << 5);
      gload_lds16(BT + (size_t)(n0 + n) * K + kt * 64 + lc * 8,
                  &sB[d][h][(size_t)s * 8]);
    }
  };

  // prologue: tile0 full (8 loads) + tile1 {Ah0,Bh0,Bh1} (6 loads)
  stA(0, 0, 0); stA(0, 1, 0); stB(0, 0, 0); stB(0, 1, 0);
  stA(1, 0, 1); stB(1, 0, 1); stB(1, 1, 1);
  asm volatile("s_waitcnt vmcnt(6)\n\ts_barrier" ::: "memory");

#pragma unroll 1
  for (int u = 0; u < KT / 2; ++u) {
    const int T1 = 2 * u + 1;
    const int tn0 = (2 * u + 2 < KT) ? 2 * u + 2 : 2 * u;  // dummy: re-stage resident
    const int tn1 = (2 * u + 3 < KT) ? 2 * u + 3 : T1;
    const char* A00 = (const char*)&sA[0][0][0];
    const char* A01 = (const char*)&sA[0][1][0];
    const char* A10 = (const char*)&sA[1][0][0];
    const char* A11 = (const char*)&sA[1][1][0];
    const char* B00 = (const char*)&sB[0][0][0];
    const char* B01 = (const char*)&sB[0][1][0];
    const char* B10 = (const char*)&sB[1][0][0];
    const char* B11 = (const char*)&sB[1][1][0];

    bf16x8 afl[4][2], afh[4][2], bfl[2][2], bfh[2][2];

    // ---------------- phase 1 (tile T0, d0) ----------------
#pragma unroll
    for (int i = 0; i < 4; ++i)
#pragma unroll
      for (int ks = 0; ks < 2; ++ks) afl[i][ks] = *(const bf16x8*)(A00 + oA[i][ks]);
#pragma unroll
    for (int j = 0; j < 2; ++j)
#pragma unroll
      for (int ks = 0; ks < 2; ++ks) bfl[j][ks] = *(const bf16x8*)(B00 + oB[j][ks]);
    stA(1, 1, T1);
    asm volatile("s_waitcnt lgkmcnt(8)" ::: "memory");
    asm volatile("s_barrier" ::: "memory");
    asm volatile("s_waitcnt lgkmcnt(0)" ::: "memory");
    __builtin_amdgcn_s_setprio(1);
#pragma unroll
    for (int i = 0; i < 4; ++i)
#pragma unroll
      for (int j = 0; j < 2; ++j)
#pragma unroll
        for (int ks = 0; ks < 2; ++ks)
          acc[i][j] = mfma16(afl[i][ks], bfl[j][ks], acc[i][j]);
    __builtin_amdgcn_s_setprio(0);
    asm volatile("s_barrier" ::: "memory");

    // ---------------- phase 2 ----------------
#pragma unroll
    for (int j = 0; j < 2; ++j)
#pragma unroll
      for (int ks = 0; ks < 2; ++ks) bfh[j][ks] = *(const bf16x8*)(B01 + oB[j][ks]);
    stA(0, 0, tn0);
    asm volatile("s_barrier" ::: "memory");
    asm volatile("s_waitcnt lgkmcnt(0)" ::: "memory");
    __builtin_amdgcn_s_setprio(1);
#pragma unroll
    for (int i = 0; i < 4; ++i)
#pragma unroll
      for (int j = 0; j < 2; ++j)
#pragma unroll
        for (int ks = 0; ks < 2; ++ks)
          acc[i][2 + j] = mfma16(afl[i][ks], bfh[j][ks], acc[i][2 + j]);
    __builtin_amdgcn_s_setprio(0);
    asm volatile("s_barrier" ::: "memory");

    // ---------------- phase 3 ----------------
#pragma unroll
    for (int i = 0; i < 4; ++i)
#pragma unroll
      for (int ks = 0; ks < 2; ++ks) afh[i][ks] = *(const bf16x8*)(A01 + oA[i][ks]);
    stB(0, 0, tn0);
    asm volatile("s_barrier" ::: "memory");
    asm volatile("s_waitcnt lgkmcnt(0)" ::: "memory");
    __builtin_amdgcn_s_setprio(1);
#pragma unroll
    for (int i = 0; i < 4; ++i)
#pragma unroll
      for (int j = 0; j < 2; ++j)
#pragma unroll
        for (int ks = 0; ks < 2; ++ks)
          acc[4 + i][2 + j] = mfma16(afh[i][ks], bfh[j][ks], acc[4 + i][2 + j]);
    __builtin_amdgcn_s_setprio(0);
    asm volatile("s_barrier" ::: "memory");

    // ---------------- phase 4 ----------------
    stB(0, 1, tn0);
    asm volatile("s_barrier" ::: "memory");
    __builtin_amdgcn_s_setprio(1);
#pragma unroll
    for (int i = 0; i < 4; ++i)
#pragma unroll
      for (int j = 0; j < 2; ++j)
#pragma unroll
        for (int ks = 0; ks < 2; ++ks)
          acc[4 + i][j] = mfma16(afh[i][ks], bfl[j][ks], acc[4 + i][j]);
    __builtin_amdgcn_s_setprio(0);
    asm volatile("s_waitcnt vmcnt(6)\n\ts_barrier" ::: "memory");

    // ---------------- phase 5 (tile T1, d1) ----------------
#pragma unroll
    for (int i = 0; i < 4; ++i)
#pragma unroll
      for (int ks = 0; ks < 2; ++ks) afl[i][ks] = *(const bf16x8*)(A10 + oA[i][ks]);
#pragma unroll
    for (int j = 0; j < 2; ++j)
#pragma unroll
      for (int ks = 0; ks < 2; ++ks) bfl[j][ks] = *(const bf16x8*)(B10 + oB[j][ks]);
    stA(0, 1, tn0);
    asm volatile("s_waitcnt lgkmcnt(8)" ::: "memory");
    asm volatile("s_barrier" ::: "memory");
    asm volatile("s_waitcnt lgkmcnt(0)" ::: "memory");
    __builtin_amdgcn_s_setprio(1);
#pragma unroll
    for (int i = 0; i < 4; ++i)
#pragma unroll
      for (int j = 0; j < 2; ++j)
#pragma unroll
        for (int ks = 0; ks < 2; ++ks)
          acc[i][j] = mfma16(afl[i][ks], bfl[j][ks], acc[i][j]);
    __builtin_amdgcn_s_setprio(0);
    asm volatile("s_barrier" ::: "memory");

    // ---------------- phase 6 ----------------
#pragma unroll
    for (int j = 0; j < 2; ++j)
#pragma unroll
      for (int ks = 0; ks < 2; ++ks) bfh[j][ks] = *(const bf16x8*)(B11 + oB[j][ks]);
    stA(1, 0, tn1);
    asm volatile("s_barrier" ::: "memory");
    asm volatile("s_waitcnt lgkmcnt(0)" ::: "memory");
    __builtin_amdgcn_s_setprio(1);
#pragma unroll
    for (int i = 0; i < 4; ++i)
#pragma unroll
      for (int j = 0; j < 2; ++j)
#pragma unroll
        for (int ks = 0; ks < 2; ++ks)
          acc[i][2 + j] = mfma16(afl[i][ks], bfh[j][ks], acc[i][2 + j]);
    __builtin_amdgcn_s_setprio(0);
    asm volatile("s_barrier" ::: "memory");

    // ---------------- phase 7 ----------------
#pragma unroll
    for (int i = 0; i < 4; ++i)
#pragma unroll
      for (int ks = 0; ks < 2; ++ks) afh[i][ks] = *(const bf16x8*)(A11 + oA[i][ks]);
    stB(1, 0, tn1);
    asm volatile("s_barrier" ::: "memory");
    asm volatile("s_waitcnt lgkmcnt(0)" ::: "memory");
    __builtin_amdgcn_s_setprio(1);
#pragma unroll
    for (int i = 0; i < 4; ++i)
#pragma unroll
      for (int j = 0; j < 2; ++j)
#pragma unroll
        for (int ks = 0; ks < 2; ++ks)
          acc[4 + i][2 + j] = mfma16(afh[i][ks], bfh[j][ks], acc[4 + i][2 + j]);
    __builtin_amdgcn_s_setprio(0);
    asm volatile("s_barrier" ::: "memory");

    // ---------------- phase 8 ----------------
    stB(1, 1, tn1);
    asm volatile("s_barrier" ::: "memory");
    __builtin_amdgcn_s_setprio(1);
#pragma unroll
    for (int i = 0; i < 4; ++i)
#pragma unroll
      for (int j = 0; j < 2; ++j)
#pragma unroll
        for (int ks = 0; ks < 2; ++ks)
          acc[4 + i][j] = mfma16(afh[i][ks], bfl[j][ks], acc[4 + i][j]);
    __builtin_amdgcn_s_setprio(0);
    asm volatile("s_waitcnt vmcnt(6)\n\ts_barrier" ::: "memory");
  }
  asm volatile("s_waitcnt vmcnt(0)" ::: "memory");

  // ---- epilogue ----
  const int cb = n0 >> 10;          // uniform per block (256 | 1024)
#pragma unroll
  for (int i = 0; i < 8; ++i) {
#pragma unroll
    for (int jj = 0; jj < 4; ++jj) {
      const int n = n0 + wn * 64 + jj * 16 + lr;
      const int m0r = m0 + wm * 128 + i * 16 + kg * 4;
      if (MODE == 0) {
        const int nn = n & 1023;
        if (cb == 0) {
          const float b_ = bias0[nn];
#pragma unroll
          for (int r = 0; r < 4; ++r)
            Qo[(size_t)(m0r + r) * ADIM + nn] = (bf16)(acc[i][jj][r] + b_);
        } else if (cb == 1) {
          const float b_ = bias1[nn];
#pragma unroll
          for (int r = 0; r < 4; ++r) {
            float v = acc[i][jj][r] + b_;
            Ko[(size_t)(m0r + r) * ADIM + nn] = (bf16)(v > 0.f ? v + 1.f : __expf(v));
          }
        } else {
          const float b_ = bias2[nn];
          const int bb = m0r >> 11, t0c = m0r & 2047;
          bf16x4 pk;
#pragma unroll
          for (int r = 0; r < 4; ++r) pk[r] = (bf16)(acc[i][jj][r] + b_);
          *(bf16x4*)&Vto[((size_t)bb * ADIM + nn) * ASEQ + t0c] = pk;
        }
      } else {
        const float b_ = bias0[n];
#pragma unroll
        for (int r = 0; r < 4; ++r)
          outF[(size_t)(m0r + r) * ADIM + n] = acc[i][jj][r] + b_;
      }
    }
  }
}

// --------- windowed decay attention: one (batch, 64-row q-tile) per WG ---------
__global__ __launch_bounds__(256) void k_attn(
    const bf16* __restrict__ Qg, const bf16* __restrict__ Kg,
    const bf16* __restrict__ Vt, bf16* __restrict__ Rb,
    const float* __restrict__ decay_param)
{
  const int b = blockIdx.y;
  const int T0 = blockIdx.x * 64;
  const int tid = threadIdx.x;
  const int l = tid & 63, w = tid >> 6;
  const int lr = l & 15, lk = (l >> 4) * 8;

  const float dp = decay_param[0];
  const float decay = 1.f / (1.f + __expf(-dp));
  const float l2d = __log2f(decay);

  __shared__ alignas(16) bf16 lQ[2][64 * 32];
  __shared__ alignas(16) bf16 lK[2][128 * 32];
  __shared__ alignas(16) bf16 lV[2][128 * 32];
  __shared__ alignas(16) bf16 lP[64 * 136];

  const bf16* Qb = Qg + (size_t)(b * ASEQ + T0) * ADIM;

  auto stageQK = [&](int buf, int k0) {
    {
      const bf16* g = Qb + (size_t)(w * 16 + (l >> 2)) * ADIM + k0 + (l & 3) * 8;
      gload_lds16(g, &lQ[buf][w * 16 * 32]);
    }
#pragma unroll
    for (int cc = 0; cc < 2; ++cc) {
      int c = 2 * w + cc;
      int sg = T0 - 64 + c * 16 + (l >> 2);
      if (sg < 0) sg = 0;
      const bf16* g = Kg + (size_t)(b * ASEQ + sg) * ADIM + k0 + (l & 3) * 8;
      gload_lds16(g, &lK[buf][c * 16 * 32]);
    }
  };

  f32x4 sc[4][2] = {};
  stageQK(0, 0);
  __syncthreads();
  for (int kt = 0; kt < 32; ++kt) {
    int cur = kt & 1;
    if (kt + 1 < 32) stageQK(cur ^ 1, (kt + 1) * 32);
    bf16x8 af[4], bfr[2];
#pragma unroll
    for (int i = 0; i < 4; ++i)
      af[i] = *(const bf16x8*)&lQ[cur][(i * 16 + lr) * 32 + lk];
#pragma unroll
    for (int j = 0; j < 2; ++j)
      bfr[j] = *(const bf16x8*)&lK[cur][(w * 32 + j * 16 + lr) * 32 + lk];
#pragma unroll
    for (int i = 0; i < 4; ++i)
#pragma unroll
      for (int j = 0; j < 2; ++j)
        sc[i][j] = mfma16(af[i], bfr[j], sc[i][j]);
    __syncthreads();
  }

  const int er = (l >> 4) * 4, ec = l & 15;
#pragma unroll
  for (int i = 0; i < 4; ++i)
#pragma unroll
    for (int j = 0; j < 2; ++j)
#pragma unroll
      for (int r = 0; r < 4; ++r) {
        int tl = i * 16 + er + r;
        int sl = w * 32 + j * 16 + ec;
        int sg = T0 - 64 + sl;
        int delta = (T0 + tl) - 1 - sg;
        float wgt = (delta >= 0 && delta < 64 && sg >= 0)
                        ? exp2f((float)delta * l2d) : 0.f;
        lP[tl * 136 + sl] = (bf16)(sc[i][j][r] * wgt);
      }

  auto stageV = [&](int buf, int g) {
    int nc = g >> 2, ks = g & 3;
#pragma unroll
    for (int cc = 0; cc < 2; ++cc) {
      int c = 2 * w + cc;
      int drow = nc * 128 + c * 16 + (l >> 2);
      int scol = T0 - 64 + ks * 32 + (l & 3) * 8;
      if (scol < 0) scol = 0;
      const bf16* gv = Vt + ((size_t)b * ADIM + drow) * ASEQ + scol;
      gload_lds16(gv, &lV[buf][c * 16 * 32]);
    }
  };

  f32x4 o[4][2] = {};
  stageV(0, 0);
  __syncthreads();

  for (int g = 0; g < 32; ++g) {
    int cur = g & 1;
    if (g + 1 < 32) stageV(cur ^ 1, g + 1);
    int nc = g >> 2, ks = g & 3;
    bf16x8 af[4], bfr[2];
#pragma unroll
    for (int i = 0; i < 4; ++i)
      af[i] = *(const bf16x8*)&lP[(i * 16 + lr) * 136 + ks * 32 + lk];
#pragma unroll
    for (int j = 0; j < 2; ++j)
      bfr[j] = *(const bf16x8*)&lV[cur][(w * 32 + j * 16 + lr) * 32 + lk];
#pragma unroll
    for (int i = 0; i < 4; ++i)
#pragma unroll
      for (int j = 0; j < 2; ++j)
        o[i][j] = mfma16(af[i], bfr[j], o[i][j]);
    if (ks == 3) {
#pragma unroll
      for (int i = 0; i < 4; ++i)
#pragma unroll
        for (int j = 0; j < 2; ++j) {
#pragma unroll
          for (int r = 0; r < 4; ++r) {
            int tl = i * 16 + er + r;
            int dl = nc * 128 + w * 32 + j * 16 + ec;
            Rb[(size_t)(b * ASEQ + T0 + tl) * ADIM + dl] = (bf16)o[i][j][r];
          }
#pragma unroll
          for (int r = 0; r < 4; ++r) o[i][j][r] = 0.f;
        }
    }
    __syncthreads();
  }
}

extern "C" void kernel_launch(void* const* d_in, const int* in_sizes, int n_in,
                              void* d_out, int out_size, void* d_ws, size_t ws_size,
                              hipStream_t stream) {
  const float* x  = (const float*)d_in[0];
  const float* Wq = (const float*)d_in[1];
  const float* bq = (const float*)d_in[2];
  const float* Wk = (const float*)d_in[3];
  const float* bk = (const float*)d_in[4];
  const float* Wv = (const float*)d_in[5];
  const float* bv = (const float*)d_in[6];
  const float* Wo = (const float*)d_in[7];
  const float* bo = (const float*)d_in[8];
  const float* dp = (const float*)d_in[9];
  float* out = (float*)d_out;

  char* ws = (char*)d_ws;
  bf16* Xb  = (bf16*)(ws + ((size_t)0 << 20));    // [16384][1024]
  bf16* Qb  = (bf16*)(ws + ((size_t)32 << 20));
  bf16* Kb  = (bf16*)(ws + ((size_t)64 << 20));
  bf16* Vtb = (bf16*)(ws + ((size_t)96 << 20));   // [8][1024][2048]
  bf16* Rbb = (bf16*)(ws + ((size_t)128 << 20));
  bf16* WcT = (bf16*)(ws + ((size_t)160 << 20));  // [3072][1024]
  bf16* WoT = (bf16*)(ws + ((size_t)166 << 20));  // [1024][1024]

  const int M = ABATCH * ASEQ;  // 16384

  k_prep<<<3072, 256, 0, stream>>>(x, Xb, (M * ADIM) / 4,
                                   Wq, Wk, Wv, Wo, WcT, WoT);
  k_g8f<0><<<768, 512, 0, stream>>>(
      Xb, WcT, bq, bk, bv, Qb, Kb, Vtb, nullptr, 12);
  k_attn<<<dim3(32, 8), 256, 0, stream>>>(Qb, Kb, Vtb, Rbb, dp);
  k_g8f<1><<<256, 512, 0, stream>>>(
      Rbb, WoT, bo, nullptr, nullptr, nullptr, nullptr, nullptr, out, 4);
}

// Round 13
// 186.375 us; speedup vs baseline: 1.4727x; 1.1553x over previous
//
#include <hip/hip_runtime.h>
#include <cstdint>
#include <cstddef>

typedef __bf16 bf16;
typedef __attribute__((ext_vector_type(8))) __bf16 bf16x8;
typedef __attribute__((ext_vector_type(4))) __bf16 bf16x4;
typedef __attribute__((ext_vector_type(4))) float f32x4;
typedef __attribute__((ext_vector_type(4))) int i32x4;

#define ADIM 1024
#define ASEQ 2048
#define ABATCH 8

__device__ __forceinline__ void gload_lds16(const void* g, void* l) {
  __builtin_amdgcn_global_load_lds(
      (const __attribute__((address_space(1))) void*)g,
      (__attribute__((address_space(3))) void*)l,
      16, 0, 0);
}

__device__ __forceinline__ f32x4 mfma16(bf16x8 a, bf16x8 b, f32x4 c) {
  return __builtin_amdgcn_mfma_f32_16x16x32_bf16(a, b, c, 0, 0, 0);
}
__device__ __forceinline__ i32x4 mfma8i(i32x4 a, i32x4 b, i32x4 c) {
  return __builtin_amdgcn_mfma_i32_16x16x64_i8(a, b, c, 0, 0, 0);
}

// ------- prep: transpose weights to B^T bf16 (coalesced both sides) -------
__global__ __launch_bounds__(256) void k_prep_w(
    const float* __restrict__ Wq, const float* __restrict__ Wk,
    const float* __restrict__ Wv, const float* __restrict__ Wo,
    bf16* __restrict__ WcT, bf16* __restrict__ WoT) {
  const int b = blockIdx.x;
  const int which = b >> 8, t = b & 255;
  const int n0 = (t & 15) * 64, k0 = (t >> 4) * 64;
  const float* W = (which == 0) ? Wq : (which == 1) ? Wk : (which == 2) ? Wv : Wo;
  bf16* out = (which < 3) ? (WcT + (size_t)which * ADIM * ADIM) : WoT;

  __shared__ float tile[64][69];
  const int r = threadIdx.x >> 4, c4 = (threadIdx.x & 15) * 4;
#pragma unroll
  for (int p = 0; p < 4; ++p) {
    float4 f = *(const float4*)&W[(size_t)(k0 + p * 16 + r) * ADIM + n0 + c4];
    tile[p * 16 + r][c4 + 0] = f.x;
    tile[p * 16 + r][c4 + 1] = f.y;
    tile[p * 16 + r][c4 + 2] = f.z;
    tile[p * 16 + r][c4 + 3] = f.w;
  }
  __syncthreads();
#pragma unroll
  for (int p = 0; p < 4; ++p) {
    const int nn = p * 16 + r;
    bf16x4 o;
#pragma unroll
    for (int j = 0; j < 4; ++j) o[j] = (bf16)tile[c4 + j][nn];
    *(bf16x4*)&out[(size_t)(n0 + nn) * ADIM + k0 + c4] = o;
  }
}

// ------- quantize rows to i8 + per-row scale. One 64-lane wave per row. -------
// rows [0,16384): x (f32) -> Xq, sx.  rows [16384,19456): WcT (bf16) -> WcQ, swc.
__global__ __launch_bounds__(256) void k_q(
    const float* __restrict__ x, const bf16* __restrict__ WcT,
    signed char* __restrict__ Xq, float* __restrict__ sx,
    signed char* __restrict__ WcQ, float* __restrict__ swc) {
  const int row = blockIdx.x * 4 + (threadIdx.x >> 6);
  const int l = threadIdx.x & 63;
  float v[16];
  if (row < 16384) {
    const float4* p = (const float4*)&x[(size_t)row * ADIM + l * 16];
#pragma unroll
    for (int g = 0; g < 4; ++g) {
      float4 f = p[g];
      v[g * 4 + 0] = f.x; v[g * 4 + 1] = f.y; v[g * 4 + 2] = f.z; v[g * 4 + 3] = f.w;
    }
  } else {
    const bf16x8* p = (const bf16x8*)&WcT[(size_t)(row - 16384) * ADIM + l * 16];
#pragma unroll
    for (int g = 0; g < 2; ++g) {
      bf16x8 f = p[g];
#pragma unroll
      for (int e = 0; e < 8; ++e) v[g * 8 + e] = (float)f[e];
    }
  }
  float m = 0.f;
#pragma unroll
  for (int e = 0; e < 16; ++e) m = fmaxf(m, fabsf(v[e]));
#pragma unroll
  for (int off = 32; off >= 1; off >>= 1) m = fmaxf(m, __shfl_xor(m, off));
  m = fmaxf(m, 1e-20f);
  const float inv = 127.f / m;
  i32x4 pk;
#pragma unroll
  for (int g = 0; g < 4; ++g) {
    int word = 0;
#pragma unroll
    for (int e = 0; e < 4; ++e) {
      int q = __float2int_rn(v[g * 4 + e] * inv);
      q = max(-127, min(127, q));
      word |= (q & 255) << (e * 8);
    }
    pk[g] = word;
  }
  if (row < 16384) {
    *(i32x4*)&Xq[(size_t)row * ADIM + l * 16] = pk;
    if (l == 0) sx[row] = m / 127.f;
  } else {
    *(i32x4*)&WcQ[(size_t)(row - 16384) * ADIM + l * 16] = pk;
    if (l == 0) swc[row - 16384] = m / 127.f;
  }
}

// ====== i8 QKV GEMM: 256x256 tile, BK=128 i8 (same byte geometry as r8) ======
// acc_i32 -> fp32 via sx[m]*swc[n] (exact scale factoring). Dbuf, 1 fence/step,
// KT=8. LDS 128 KiB. Swizzle/ledger identical to the r8-proven kernel.
__global__ __launch_bounds__(512, 2) void k_qkv8(
    const signed char* __restrict__ A, const signed char* __restrict__ BT,
    const float* __restrict__ sx, const float* __restrict__ swc,
    const float* __restrict__ bias0, const float* __restrict__ bias1,
    const float* __restrict__ bias2,
    bf16* __restrict__ Qo, bf16* __restrict__ Ko, bf16* __restrict__ Vto)
{
  constexpr int K = 1024;           // bytes per row
  constexpr int KT = 8;             // 8 steps of BK=128 bytes
  const int nwg = gridDim.x;
  const int cpx = nwg >> 3;
  const int flat = blockIdx.x;
  const int sw = (flat & 7) * cpx + (flat >> 3);
  const int bx = sw % 12, by = sw / 12;
  const int m0 = by * 256, n0 = bx * 256;

  const int tid = threadIdx.x;
  const int l = tid & 63, w = tid >> 6;
  const int wm = w >> 2, wn = w & 3;
  const int lr = l & 15, kg = l >> 4;

  __shared__ alignas(16) signed char sA[2][256 * 128];   // 64 KiB
  __shared__ alignas(16) signed char sB[2][256 * 128];   // 64 KiB

  i32x4 acc[8][4] = {};

  // ds_read byte offsets for ks=0 (ks=1: ^64). Row = 128B = 8 slots of 16B.
  int oA[8], oB[4];
#pragma unroll
  for (int i = 0; i < 8; ++i) {
    int r = wm * 128 + i * 16 + lr;
    oA[i] = (r * 8 + (kg ^ (r & 7))) * 16;
  }
#pragma unroll
  for (int j = 0; j < 4; ++j) {
    int r = wn * 64 + j * 16 + lr;
    oB[j] = (r * 8 + (kg ^ (r & 7))) * 16;
  }

  auto stA = [&](int c, int kt, int chunk) {
    int s = chunk * 512 + tid;
    int prow = s >> 3, ps = s & 7;
    int lc = ps ^ (prow & 7);
    gload_lds16(A + (size_t)(m0 + prow) * K + kt * 128 + lc * 16,
                &sA[c][(size_t)s * 16]);
  };
  auto stB = [&](int c, int kt, int chunk) {
    int s = chunk * 512 + tid;
    int prow = s >> 3, ps = s & 7;
    int lc = ps ^ (prow & 7);
    gload_lds16(BT + (size_t)(n0 + prow) * K + kt * 128 + lc * 16,
                &sB[c][(size_t)s * 16]);
  };

#pragma unroll
  for (int ch = 0; ch < 4; ++ch) { stA(0, 0, ch); stB(0, 0, ch); }
  asm volatile("s_waitcnt vmcnt(0)\n\ts_barrier" ::: "memory");

  for (int t = 0; t < KT; ++t) {
    const int c = t & 1;
    const char* bA = (const char*)&sA[c][0];
    const char* bB = (const char*)&sB[c][0];

    i32x4 af[8], bfr[4];
#pragma unroll
    for (int i = 0; i < 8; ++i) af[i] = *(const i32x4*)(bA + oA[i]);
#pragma unroll
    for (int j = 0; j < 4; ++j) bfr[j] = *(const i32x4*)(bB + oB[j]);

    if (t + 1 < KT) {
#pragma unroll
      for (int ch = 0; ch < 4; ++ch) { stA(c ^ 1, t + 1, ch); stB(c ^ 1, t + 1, ch); }
    }

    __builtin_amdgcn_s_setprio(1);
#pragma unroll
    for (int i = 0; i < 8; ++i)
#pragma unroll
      for (int j = 0; j < 4; ++j)
        acc[i][j] = mfma8i(af[i], bfr[j], acc[i][j]);
    __builtin_amdgcn_s_setprio(0);

#pragma unroll
    for (int i = 0; i < 8; ++i) af[i] = *(const i32x4*)(bA + (oA[i] ^ 64));
#pragma unroll
    for (int j = 0; j < 4; ++j) bfr[j] = *(const i32x4*)(bB + (oB[j] ^ 64));

    __builtin_amdgcn_s_setprio(1);
#pragma unroll
    for (int i = 0; i < 8; ++i)
#pragma unroll
      for (int j = 0; j < 4; ++j)
        acc[i][j] = mfma8i(af[i], bfr[j], acc[i][j]);
    __builtin_amdgcn_s_setprio(0);

    asm volatile("s_waitcnt vmcnt(0)\n\ts_barrier" ::: "memory");
  }

  // ---- dequant epilogue ----
  const int cb = n0 >> 10;          // uniform per block
#pragma unroll
  for (int i = 0; i < 8; ++i) {
#pragma unroll
    for (int jj = 0; jj < 4; ++jj) {
      const int n = n0 + wn * 64 + jj * 16 + lr;
      const int m0r = m0 + wm * 128 + i * 16 + kg * 4;
      const int nn = n & 1023;
      const float swn = swc[n];
      const float4 s4 = *(const float4*)&sx[m0r];
      float de[4];
      de[0] = (float)acc[i][jj][0] * s4.x * swn;
      de[1] = (float)acc[i][jj][1] * s4.y * swn;
      de[2] = (float)acc[i][jj][2] * s4.z * swn;
      de[3] = (float)acc[i][jj][3] * s4.w * swn;
      if (cb == 0) {
        const float b_ = bias0[nn];
#pragma unroll
        for (int r = 0; r < 4; ++r)
          Qo[(size_t)(m0r + r) * ADIM + nn] = (bf16)(de[r] + b_);
      } else if (cb == 1) {
        const float b_ = bias1[nn];
#pragma unroll
        for (int r = 0; r < 4; ++r) {
          float v = de[r] + b_;
          Ko[(size_t)(m0r + r) * ADIM + nn] = (bf16)(v > 0.f ? v + 1.f : __expf(v));
        }
      } else {
        const float b_ = bias2[nn];
        const int bb = m0r >> 11, t0c = m0r & 2047;
        bf16x4 pk;
#pragma unroll
        for (int r = 0; r < 4; ++r) pk[r] = (bf16)(de[r] + b_);
        *(bf16x4*)&Vto[((size_t)bb * ADIM + nn) * ASEQ + t0c] = pk;
      }
    }
  }
}

// ====== bf16 out-GEMM (r8-proven): 256x256 BK=64, dbuf, 1 fence/step ======
__global__ __launch_bounds__(512, 2) void k_gout(
    const bf16* __restrict__ A, const bf16* __restrict__ BT,
    const float* __restrict__ bias0, float* __restrict__ outF)
{
  constexpr int K = 1024;
  constexpr int KT = 16;
  const int nwg = gridDim.x;
  const int cpx = nwg >> 3;
  const int flat = blockIdx.x;
  const int sw = (flat & 7) * cpx + (flat >> 3);
  const int bx = sw % 4, by = sw / 4;
  const int m0 = by * 256, n0 = bx * 256;

  const int tid = threadIdx.x;
  const int l = tid & 63, w = tid >> 6;
  const int wm = w >> 2, wn = w & 3;
  const int lr = l & 15, kg = l >> 4;

  __shared__ alignas(16) bf16 sA[2][256 * 64];
  __shared__ alignas(16) bf16 sB[2][256 * 64];

  f32x4 acc[8][4] = {};

  int oA[8], oB[4];
#pragma unroll
  for (int i = 0; i < 8; ++i) {
    int r = wm * 128 + i * 16 + lr;
    oA[i] = (r * 8 + (kg ^ (r & 7))) * 16;
  }
#pragma unroll
  for (int j = 0; j < 4; ++j) {
    int r = wn * 64 + j * 16 + lr;
    oB[j] = (r * 8 + (kg ^ (r & 7))) * 16;
  }

  auto stA = [&](int c, int kt, int chunk) {
    int s = chunk * 512 + tid;
    int prow = s >> 3, ps = s & 7;
    int lc = ps ^ (prow & 7);
    gload_lds16(A + (size_t)(m0 + prow) * K + kt * 64 + lc * 8,
                &sA[c][(size_t)s * 8]);
  };
  auto stB = [&](int c, int kt, int chunk) {
    int s = chunk * 512 + tid;
    int prow = s >> 3, ps = s & 7;
    int lc = ps ^ (prow & 7);
    gload_lds16(BT + (size_t)(n0 + prow) * K + kt * 64 + lc * 8,
                &sB[c][(size_t)s * 8]);
  };

#pragma unroll
  for (int ch = 0; ch < 4; ++ch) { stA(0, 0, ch); stB(0, 0, ch); }
  asm volatile("s_waitcnt vmcnt(0)\n\ts_barrier" ::: "memory");

  for (int t = 0; t < KT; ++t) {
    const int c = t & 1;
    const char* bA = (const char*)&sA[c][0];
    const char* bB = (const char*)&sB[c][0];

    bf16x8 af[8], bfr[4];
#pragma unroll
    for (int i = 0; i < 8; ++i) af[i] = *(const bf16x8*)(bA + oA[i]);
#pragma unroll
    for (int j = 0; j < 4; ++j) bfr[j] = *(const bf16x8*)(bB + oB[j]);

    if (t + 1 < KT) {
#pragma unroll
      for (int ch = 0; ch < 4; ++ch) { stA(c ^ 1, t + 1, ch); stB(c ^ 1, t + 1, ch); }
    }

    __builtin_amdgcn_s_setprio(1);
#pragma unroll
    for (int i = 0; i < 8; ++i)
#pragma unroll
      for (int j = 0; j < 4; ++j)
        acc[i][j] = mfma16(af[i], bfr[j], acc[i][j]);
    __builtin_amdgcn_s_setprio(0);

#pragma unroll
    for (int i = 0; i < 8; ++i) af[i] = *(const bf16x8*)(bA + (oA[i] ^ 64));
#pragma unroll
    for (int j = 0; j < 4; ++j) bfr[j] = *(const bf16x8*)(bB + (oB[j] ^ 64));

    __builtin_amdgcn_s_setprio(1);
#pragma unroll
    for (int i = 0; i < 8; ++i)
#pragma unroll
      for (int j = 0; j < 4; ++j)
        acc[i][j] = mfma16(af[i], bfr[j], acc[i][j]);
    __builtin_amdgcn_s_setprio(0);

    asm volatile("s_waitcnt vmcnt(0)\n\ts_barrier" ::: "memory");
  }

#pragma unroll
  for (int i = 0; i < 8; ++i) {
#pragma unroll
    for (int jj = 0; jj < 4; ++jj) {
      const int n = n0 + wn * 64 + jj * 16 + lr;
      const int m0r = m0 + wm * 128 + i * 16 + kg * 4;
      const float b_ = bias0[n];
#pragma unroll
      for (int r = 0; r < 4; ++r)
        outF[(size_t)(m0r + r) * ADIM + n] = acc[i][jj][r] + b_;
    }
  }
}

// --------- windowed decay attention (unchanged) ---------
__global__ __launch_bounds__(256) void k_attn(
    const bf16* __restrict__ Qg, const bf16* __restrict__ Kg,
    const bf16* __restrict__ Vt, bf16* __restrict__ Rb,
    const float* __restrict__ decay_param)
{
  const int b = blockIdx.y;
  const int T0 = blockIdx.x * 64;
  const int tid = threadIdx.x;
  const int l = tid & 63, w = tid >> 6;
  const int lr = l & 15, lk = (l >> 4) * 8;

  const float dp = decay_param[0];
  const float decay = 1.f / (1.f + __expf(-dp));
  const float l2d = __log2f(decay);

  __shared__ alignas(16) bf16 lQ[2][64 * 32];
  __shared__ alignas(16) bf16 lK[2][128 * 32];
  __shared__ alignas(16) bf16 lV[2][128 * 32];
  __shared__ alignas(16) bf16 lP[64 * 136];

  const bf16* Qb = Qg + (size_t)(b * ASEQ + T0) * ADIM;

  auto stageQK = [&](int buf, int k0) {
    {
      const bf16* g = Qb + (size_t)(w * 16 + (l >> 2)) * ADIM + k0 + (l & 3) * 8;
      gload_lds16(g, &lQ[buf][w * 16 * 32]);
    }
#pragma unroll
    for (int cc = 0; cc < 2; ++cc) {
      int c = 2 * w + cc;
      int sg = T0 - 64 + c * 16 + (l >> 2);
      if (sg < 0) sg = 0;
      const bf16* g = Kg + (size_t)(b * ASEQ + sg) * ADIM + k0 + (l & 3) * 8;
      gload_lds16(g, &lK[buf][c * 16 * 32]);
    }
  };

  f32x4 sc[4][2] = {};
  stageQK(0, 0);
  __syncthreads();
  for (int kt = 0; kt < 32; ++kt) {
    int cur = kt & 1;
    if (kt + 1 < 32) stageQK(cur ^ 1, (kt + 1) * 32);
    bf16x8 af[4], bfr[2];
#pragma unroll
    for (int i = 0; i < 4; ++i)
      af[i] = *(const bf16x8*)&lQ[cur][(i * 16 + lr) * 32 + lk];
#pragma unroll
    for (int j = 0; j < 2; ++j)
      bfr[j] = *(const bf16x8*)&lK[cur][(w * 32 + j * 16 + lr) * 32 + lk];
#pragma unroll
    for (int i = 0; i < 4; ++i)
#pragma unroll
      for (int j = 0; j < 2; ++j)
        sc[i][j] = mfma16(af[i], bfr[j], sc[i][j]);
    __syncthreads();
  }

  const int er = (l >> 4) * 4, ec = l & 15;
#pragma unroll
  for (int i = 0; i < 4; ++i)
#pragma unroll
    for (int j = 0; j < 2; ++j)
#pragma unroll
      for (int r = 0; r < 4; ++r) {
        int tl = i * 16 + er + r;
        int sl = w * 32 + j * 16 + ec;
        int sg = T0 - 64 + sl;
        int delta = (T0 + tl) - 1 - sg;
        float wgt = (delta >= 0 && delta < 64 && sg >= 0)
                        ? exp2f((float)delta * l2d) : 0.f;
        lP[tl * 136 + sl] = (bf16)(sc[i][j][r] * wgt);
      }

  auto stageV = [&](int buf, int g) {
    int nc = g >> 2, ks = g & 3;
#pragma unroll
    for (int cc = 0; cc < 2; ++cc) {
      int c = 2 * w + cc;
      int drow = nc * 128 + c * 16 + (l >> 2);
      int scol = T0 - 64 + ks * 32 + (l & 3) * 8;
      if (scol < 0) scol = 0;
      const bf16* gv = Vt + ((size_t)b * ADIM + drow) * ASEQ + scol;
      gload_lds16(gv, &lV[buf][c * 16 * 32]);
    }
  };

  f32x4 o[4][2] = {};
  stageV(0, 0);
  __syncthreads();

  for (int g = 0; g < 32; ++g) {
    int cur = g & 1;
    if (g + 1 < 32) stageV(cur ^ 1, g + 1);
    int nc = g >> 2, ks = g & 3;
    bf16x8 af[4], bfr[2];
#pragma unroll
    for (int i = 0; i < 4; ++i)
      af[i] = *(const bf16x8*)&lP[(i * 16 + lr) * 136 + ks * 32 + lk];
#pragma unroll
    for (int j = 0; j < 2; ++j)
      bfr[j] = *(const bf16x8*)&lV[cur][(w * 32 + j * 16 + lr) * 32 + lk];
#pragma unroll
    for (int i = 0; i < 4; ++i)
#pragma unroll
      for (int j = 0; j < 2; ++j)
        o[i][j] = mfma16(af[i], bfr[j], o[i][j]);
    if (ks == 3) {
#pragma unroll
      for (int i = 0; i < 4; ++i)
#pragma unroll
        for (int j = 0; j < 2; ++j) {
#pragma unroll
          for (int r = 0; r < 4; ++r) {
            int tl = i * 16 + er + r;
            int dl = nc * 128 + w * 32 + j * 16 + ec;
            Rb[(size_t)(b * ASEQ + T0 + tl) * ADIM + dl] = (bf16)o[i][j][r];
          }
#pragma unroll
          for (int r = 0; r < 4; ++r) o[i][j][r] = 0.f;
        }
    }
    __syncthreads();
  }
}

extern "C" void kernel_launch(void* const* d_in, const int* in_sizes, int n_in,
                              void* d_out, int out_size, void* d_ws, size_t ws_size,
                              hipStream_t stream) {
  const float* x  = (const float*)d_in[0];
  const float* Wq = (const float*)d_in[1];
  const float* bq = (const float*)d_in[2];
  const float* Wk = (const float*)d_in[3];
  const float* bk = (const float*)d_in[4];
  const float* Wv = (const float*)d_in[5];
  const float* bv = (const float*)d_in[6];
  const float* Wo = (const float*)d_in[7];
  const float* bo = (const float*)d_in[8];
  const float* dp = (const float*)d_in[9];
  float* out = (float*)d_out;

  char* ws = (char*)d_ws;
  signed char* Xq  = (signed char*)(ws + ((size_t)0 << 20));   // 16 MB [16384][1024] i8
  float*       sx  = (float*)(ws + ((size_t)16 << 20));        // 64 KB
  signed char* WcQ = (signed char*)(ws + ((size_t)17 << 20));  // 3 MB [3072][1024] i8
  float*       swc = (float*)(ws + ((size_t)20 << 20));        // 12 KB
  bf16* Qb  = (bf16*)(ws + ((size_t)32 << 20));
  bf16* Kb  = (bf16*)(ws + ((size_t)64 << 20));
  bf16* Vtb = (bf16*)(ws + ((size_t)96 << 20));                // [8][1024][2048]
  bf16* Rbb = (bf16*)(ws + ((size_t)128 << 20));
  bf16* WcT = (bf16*)(ws + ((size_t)160 << 20));               // [3072][1024] bf16
  bf16* WoT = (bf16*)(ws + ((size_t)166 << 20));               // [1024][1024] bf16

  k_prep_w<<<1024, 256, 0, stream>>>(Wq, Wk, Wv, Wo, WcT, WoT);
  k_q<<<4864, 256, 0, stream>>>(x, WcT, Xq, sx, WcQ, swc);
  k_qkv8<<<768, 512, 0, stream>>>(
      Xq, WcQ, sx, swc, bq, bk, bv, Qb, Kb, Vtb);
  k_attn<<<dim3(32, 8), 256, 0, stream>>>(Qb, Kb, Vtb, Rbb, dp);
  k_gout<<<256, 512, 0, stream>>>(Rbb, WoT, bo, out);
}

// Round 14
// 182.529 us; speedup vs baseline: 1.5037x; 1.0211x over previous
//
#include <hip/hip_runtime.h>
#include <cstdint>
#include <cstddef>

typedef __bf16 bf16;
typedef __attribute__((ext_vector_type(8))) __bf16 bf16x8;
typedef __attribute__((ext_vector_type(4))) __bf16 bf16x4;
typedef __attribute__((ext_vector_type(4))) float f32x4;
typedef __attribute__((ext_vector_type(4))) int i32x4;

#define ADIM 1024
#define ASEQ 2048
#define ABATCH 8

__device__ __forceinline__ void gload_lds16(const void* g, void* l) {
  __builtin_amdgcn_global_load_lds(
      (const __attribute__((address_space(1))) void*)g,
      (__attribute__((address_space(3))) void*)l,
      16, 0, 0);
}

__device__ __forceinline__ f32x4 mfma16(bf16x8 a, bf16x8 b, f32x4 c) {
  return __builtin_amdgcn_mfma_f32_16x16x32_bf16(a, b, c, 0, 0, 0);
}
__device__ __forceinline__ i32x4 mfma8i(i32x4 a, i32x4 b, i32x4 c) {
  return __builtin_amdgcn_mfma_i32_16x16x64_i8(a, b, c, 0, 0, 0);
}

// ------- prep: transpose weights to B^T bf16 (coalesced both sides) -------
__global__ __launch_bounds__(256) void k_prep_w(
    const float* __restrict__ Wq, const float* __restrict__ Wk,
    const float* __restrict__ Wv, const float* __restrict__ Wo,
    bf16* __restrict__ WcT, bf16* __restrict__ WoT) {
  const int b = blockIdx.x;
  const int which = b >> 8, t = b & 255;
  const int n0 = (t & 15) * 64, k0 = (t >> 4) * 64;
  const float* W = (which == 0) ? Wq : (which == 1) ? Wk : (which == 2) ? Wv : Wo;
  bf16* out = (which < 3) ? (WcT + (size_t)which * ADIM * ADIM) : WoT;

  __shared__ float tile[64][69];
  const int r = threadIdx.x >> 4, c4 = (threadIdx.x & 15) * 4;
#pragma unroll
  for (int p = 0; p < 4; ++p) {
    float4 f = *(const float4*)&W[(size_t)(k0 + p * 16 + r) * ADIM + n0 + c4];
    tile[p * 16 + r][c4 + 0] = f.x;
    tile[p * 16 + r][c4 + 1] = f.y;
    tile[p * 16 + r][c4 + 2] = f.z;
    tile[p * 16 + r][c4 + 3] = f.w;
  }
  __syncthreads();
#pragma unroll
  for (int p = 0; p < 4; ++p) {
    const int nn = p * 16 + r;
    bf16x4 o;
#pragma unroll
    for (int j = 0; j < 4; ++j) o[j] = (bf16)tile[c4 + j][nn];
    *(bf16x4*)&out[(size_t)(n0 + nn) * ADIM + k0 + c4] = o;
  }
}

// ------- quantize rows to i8 + per-row scale. One 64-lane wave per row. -------
__global__ __launch_bounds__(256) void k_q(
    const float* __restrict__ x, const bf16* __restrict__ WcT,
    signed char* __restrict__ Xq, float* __restrict__ sx,
    signed char* __restrict__ WcQ, float* __restrict__ swc) {
  const int row = blockIdx.x * 4 + (threadIdx.x >> 6);
  const int l = threadIdx.x & 63;
  float v[16];
  if (row < 16384) {
    const float4* p = (const float4*)&x[(size_t)row * ADIM + l * 16];
#pragma unroll
    for (int g = 0; g < 4; ++g) {
      float4 f = p[g];
      v[g * 4 + 0] = f.x; v[g * 4 + 1] = f.y; v[g * 4 + 2] = f.z; v[g * 4 + 3] = f.w;
    }
  } else {
    const bf16x8* p = (const bf16x8*)&WcT[(size_t)(row - 16384) * ADIM + l * 16];
#pragma unroll
    for (int g = 0; g < 2; ++g) {
      bf16x8 f = p[g];
#pragma unroll
      for (int e = 0; e < 8; ++e) v[g * 8 + e] = (float)f[e];
    }
  }
  float m = 0.f;
#pragma unroll
  for (int e = 0; e < 16; ++e) m = fmaxf(m, fabsf(v[e]));
#pragma unroll
  for (int off = 32; off >= 1; off >>= 1) m = fmaxf(m, __shfl_xor(m, off));
  m = fmaxf(m, 1e-20f);
  const float inv = 127.f / m;
  i32x4 pk;
#pragma unroll
  for (int g = 0; g < 4; ++g) {
    int word = 0;
#pragma unroll
    for (int e = 0; e < 4; ++e) {
      int q = __float2int_rn(v[g * 4 + e] * inv);
      q = max(-127, min(127, q));
      word |= (q & 255) << (e * 8);
    }
    pk[g] = word;
  }
  if (row < 16384) {
    *(i32x4*)&Xq[(size_t)row * ADIM + l * 16] = pk;
    if (l == 0) sx[row] = m / 127.f;
  } else {
    *(i32x4*)&WcQ[(size_t)(row - 16384) * ADIM + l * 16] = pk;
    if (l == 0) swc[row - 16384] = m / 127.f;
  }
}

// ====== i8 QKV GEMM: 256x256 tile, BK=64B, 3-slot ring, counted vmcnt(4) ======
// r6-proven ledger: per step 4 gloads (A2+B2); read slot t%3, stage t+2 into
// (t+2)%3; end-of-step vmcnt(4)+barrier retires tile t+1 (never drains to 0).
// WAR: slot (t+2)%3 = (t-1)%3 last read 1 step + 1 barrier ago. Tail dummies.
// Row = 64B = 4 slots; swizzle slot s' = s ^ (r&3) (involution, source-side).
__global__ __launch_bounds__(512, 2) void k_qkv8(
    const signed char* __restrict__ A, const signed char* __restrict__ BT,
    const float* __restrict__ sx, const float* __restrict__ swc,
    const float* __restrict__ bias0, const float* __restrict__ bias1,
    const float* __restrict__ bias2,
    bf16* __restrict__ Qo, bf16* __restrict__ Ko, bf16* __restrict__ Vto)
{
  constexpr int K = 1024;           // bytes per row
  constexpr int KT = 16;            // steps of BK=64 bytes
  const int nwg = gridDim.x;
  const int cpx = nwg >> 3;
  const int flat = blockIdx.x;
  const int sw = (flat & 7) * cpx + (flat >> 3);
  const int bx = sw % 12, by = sw / 12;
  const int m0 = by * 256, n0 = bx * 256;

  const int tid = threadIdx.x;
  const int l = tid & 63, w = tid >> 6;
  const int wm = w >> 2, wn = w & 3;
  const int lr = l & 15, kg = l >> 4;

  __shared__ alignas(16) signed char sA[3][256 * 64];   // 48 KiB
  __shared__ alignas(16) signed char sB[3][256 * 64];   // 48 KiB

  i32x4 acc[8][4] = {};

  int oA[8], oB[4];
#pragma unroll
  for (int i = 0; i < 8; ++i) {
    int r = wm * 128 + i * 16 + lr;
    oA[i] = (r * 4 + (kg ^ (r & 3))) * 16;
  }
#pragma unroll
  for (int j = 0; j < 4; ++j) {
    int r = wn * 64 + j * 16 + lr;
    oB[j] = (r * 4 + (kg ^ (r & 3))) * 16;
  }

  auto stA = [&](int sp, int kt, int chunk) {
    int s = chunk * 512 + tid;              // linear 16B slot (1024 per tile)
    int prow = s >> 2, ps = s & 3;
    int lc = ps ^ (prow & 3);               // inverse swizzle on source
    gload_lds16(A + (size_t)(m0 + prow) * K + kt * 64 + lc * 16,
                &sA[sp][(size_t)s * 16]);
  };
  auto stB = [&](int sp, int kt, int chunk) {
    int s = chunk * 512 + tid;
    int prow = s >> 2, ps = s & 3;
    int lc = ps ^ (prow & 3);
    gload_lds16(BT + (size_t)(n0 + prow) * K + kt * 64 + lc * 16,
                &sB[sp][(size_t)s * 16]);
  };

  // prologue: tiles 0,1 (8 gloads); vmcnt(4) -> tile 0 resident, tile 1 flying
#pragma unroll
  for (int tt = 0; tt < 2; ++tt) {
    stA(tt, tt, 0); stA(tt, tt, 1);
    stB(tt, tt, 0); stB(tt, tt, 1);
  }
  asm volatile("s_waitcnt vmcnt(4)\n\ts_barrier" ::: "memory");

  for (int t = 0; t < KT; ++t) {
    const int s = t % 3;
    const char* bA = (const char*)&sA[s][0];
    const char* bB = (const char*)&sB[s][0];

    i32x4 af[8], bfr[4];
#pragma unroll
    for (int i = 0; i < 8; ++i) af[i] = *(const i32x4*)(bA + oA[i]);
#pragma unroll
    for (int j = 0; j < 4; ++j) bfr[j] = *(const i32x4*)(bB + oB[j]);

    const int tp = (t + 2 < KT) ? t + 2 : t;   // dummy tail keeps ledger uniform
    stA((t + 2) % 3, tp, 0); stA((t + 2) % 3, tp, 1);
    stB((t + 2) % 3, tp, 0); stB((t + 2) % 3, tp, 1);

    __builtin_amdgcn_s_setprio(1);
#pragma unroll
    for (int i = 0; i < 8; ++i)
#pragma unroll
      for (int j = 0; j < 4; ++j)
        acc[i][j] = mfma8i(af[i], bfr[j], acc[i][j]);
    __builtin_amdgcn_s_setprio(0);

    asm volatile("s_waitcnt vmcnt(4)\n\ts_barrier" ::: "memory");
  }
  asm volatile("s_waitcnt vmcnt(0)" ::: "memory");

  // ---- dequant epilogue ----
  const int cb = n0 >> 10;
#pragma unroll
  for (int i = 0; i < 8; ++i) {
#pragma unroll
    for (int jj = 0; jj < 4; ++jj) {
      const int n = n0 + wn * 64 + jj * 16 + lr;
      const int m0r = m0 + wm * 128 + i * 16 + kg * 4;
      const int nn = n & 1023;
      const float swn = swc[n];
      const float4 s4 = *(const float4*)&sx[m0r];
      float de[4];
      de[0] = (float)acc[i][jj][0] * s4.x * swn;
      de[1] = (float)acc[i][jj][1] * s4.y * swn;
      de[2] = (float)acc[i][jj][2] * s4.z * swn;
      de[3] = (float)acc[i][jj][3] * s4.w * swn;
      if (cb == 0) {
        const float b_ = bias0[nn];
#pragma unroll
        for (int r = 0; r < 4; ++r)
          Qo[(size_t)(m0r + r) * ADIM + nn] = (bf16)(de[r] + b_);
      } else if (cb == 1) {
        const float b_ = bias1[nn];
#pragma unroll
        for (int r = 0; r < 4; ++r) {
          float v = de[r] + b_;
          Ko[(size_t)(m0r + r) * ADIM + nn] = (bf16)(v > 0.f ? v + 1.f : __expf(v));
        }
      } else {
        const float b_ = bias2[nn];
        const int bb = m0r >> 11, t0c = m0r & 2047;
        bf16x4 pk;
#pragma unroll
        for (int r = 0; r < 4; ++r) pk[r] = (bf16)(de[r] + b_);
        *(bf16x4*)&Vto[((size_t)bb * ADIM + nn) * ASEQ + t0c] = pk;
      }
    }
  }
}

// ====== bf16 out-GEMM (r8-proven): 256x256 BK=64, dbuf, 1 fence/step ======
__global__ __launch_bounds__(512, 2) void k_gout(
    const bf16* __restrict__ A, const bf16* __restrict__ BT,
    const float* __restrict__ bias0, float* __restrict__ outF)
{
  constexpr int K = 1024;
  constexpr int KT = 16;
  const int nwg = gridDim.x;
  const int cpx = nwg >> 3;
  const int flat = blockIdx.x;
  const int sw = (flat & 7) * cpx + (flat >> 3);
  const int bx = sw % 4, by = sw / 4;
  const int m0 = by * 256, n0 = bx * 256;

  const int tid = threadIdx.x;
  const int l = tid & 63, w = tid >> 6;
  const int wm = w >> 2, wn = w & 3;
  const int lr = l & 15, kg = l >> 4;

  __shared__ alignas(16) bf16 sA[2][256 * 64];
  __shared__ alignas(16) bf16 sB[2][256 * 64];

  f32x4 acc[8][4] = {};

  int oA[8], oB[4];
#pragma unroll
  for (int i = 0; i < 8; ++i) {
    int r = wm * 128 + i * 16 + lr;
    oA[i] = (r * 8 + (kg ^ (r & 7))) * 16;
  }
#pragma unroll
  for (int j = 0; j < 4; ++j) {
    int r = wn * 64 + j * 16 + lr;
    oB[j] = (r * 8 + (kg ^ (r & 7))) * 16;
  }

  auto stA = [&](int c, int kt, int chunk) {
    int s = chunk * 512 + tid;
    int prow = s >> 3, ps = s & 7;
    int lc = ps ^ (prow & 7);
    gload_lds16(A + (size_t)(m0 + prow) * K + kt * 64 + lc * 8,
                &sA[c][(size_t)s * 8]);
  };
  auto stB = [&](int c, int kt, int chunk) {
    int s = chunk * 512 + tid;
    int prow = s >> 3, ps = s & 7;
    int lc = ps ^ (prow & 7);
    gload_lds16(BT + (size_t)(n0 + prow) * K + kt * 64 + lc * 8,
                &sB[c][(size_t)s * 8]);
  };

#pragma unroll
  for (int ch = 0; ch < 4; ++ch) { stA(0, 0, ch); stB(0, 0, ch); }
  asm volatile("s_waitcnt vmcnt(0)\n\ts_barrier" ::: "memory");

  for (int t = 0; t < KT; ++t) {
    const int c = t & 1;
    const char* bA = (const char*)&sA[c][0];
    const char* bB = (const char*)&sB[c][0];

    bf16x8 af[8], bfr[4];
#pragma unroll
    for (int i = 0; i < 8; ++i) af[i] = *(const bf16x8*)(bA + oA[i]);
#pragma unroll
    for (int j = 0; j < 4; ++j) bfr[j] = *(const bf16x8*)(bB + oB[j]);

    if (t + 1 < KT) {
#pragma unroll
      for (int ch = 0; ch < 4; ++ch) { stA(c ^ 1, t + 1, ch); stB(c ^ 1, t + 1, ch); }
    }

    __builtin_amdgcn_s_setprio(1);
#pragma unroll
    for (int i = 0; i < 8; ++i)
#pragma unroll
      for (int j = 0; j < 4; ++j)
        acc[i][j] = mfma16(af[i], bfr[j], acc[i][j]);
    __builtin_amdgcn_s_setprio(0);

#pragma unroll
    for (int i = 0; i < 8; ++i) af[i] = *(const bf16x8*)(bA + (oA[i] ^ 64));
#pragma unroll
    for (int j = 0; j < 4; ++j) bfr[j] = *(const bf16x8*)(bB + (oB[j] ^ 64));

    __builtin_amdgcn_s_setprio(1);
#pragma unroll
    for (int i = 0; i < 8; ++i)
#pragma unroll
      for (int j = 0; j < 4; ++j)
        acc[i][j] = mfma16(af[i], bfr[j], acc[i][j]);
    __builtin_amdgcn_s_setprio(0);

    asm volatile("s_waitcnt vmcnt(0)\n\ts_barrier" ::: "memory");
  }

#pragma unroll
  for (int i = 0; i < 8; ++i) {
#pragma unroll
    for (int jj = 0; jj < 4; ++jj) {
      const int n = n0 + wn * 64 + jj * 16 + lr;
      const int m0r = m0 + wm * 128 + i * 16 + kg * 4;
      const float b_ = bias0[n];
#pragma unroll
      for (int r = 0; r < 4; ++r)
        outF[(size_t)(m0r + r) * ADIM + n] = acc[i][jj][r] + b_;
    }
  }
}

// ------ windowed decay attention, 3-slot counted-vmcnt rings (r6 ledger) ------
// QK: 3 gloads/step, vmcnt(3); V: 2 gloads/step, vmcnt(2); distance-2 rings.
// Cross-phase fence: after P-writes + V(0),V(1) issue, vmcnt(2)+lgkmcnt(0)
// retires QK-tail dummies (6) + V0, leaves V1 flying.
__global__ __launch_bounds__(256) void k_attn(
    const bf16* __restrict__ Qg, const bf16* __restrict__ Kg,
    const bf16* __restrict__ Vt, bf16* __restrict__ Rb,
    const float* __restrict__ decay_param)
{
  const int b = blockIdx.y;
  const int T0 = blockIdx.x * 64;
  const int tid = threadIdx.x;
  const int l = tid & 63, w = tid >> 6;
  const int lr = l & 15, lk = (l >> 4) * 8;

  const float dp = decay_param[0];
  const float decay = 1.f / (1.f + __expf(-dp));
  const float l2d = __log2f(decay);

  __shared__ alignas(16) bf16 lQ[3][64 * 32];    // 12 KiB
  __shared__ alignas(16) bf16 lK[3][128 * 32];   // 24 KiB
  __shared__ alignas(16) bf16 lV[3][128 * 32];   // 24 KiB
  __shared__ alignas(16) bf16 lP[64 * 136];      // 17 KiB

  const bf16* Qb = Qg + (size_t)(b * ASEQ + T0) * ADIM;

  auto stageQK = [&](int buf, int k0) {
    {
      const bf16* g = Qb + (size_t)(w * 16 + (l >> 2)) * ADIM + k0 + (l & 3) * 8;
      gload_lds16(g, &lQ[buf][w * 16 * 32]);
    }
#pragma unroll
    for (int cc = 0; cc < 2; ++cc) {
      int c = 2 * w + cc;
      int sg = T0 - 64 + c * 16 + (l >> 2);
      if (sg < 0) sg = 0;
      const bf16* g = Kg + (size_t)(b * ASEQ + sg) * ADIM + k0 + (l & 3) * 8;
      gload_lds16(g, &lK[buf][c * 16 * 32]);
    }
  };

  // ---- phase 1: S = Q K^T, 3-slot ring ----
  f32x4 sc[4][2] = {};
  stageQK(0, 0);
  stageQK(1, 32);
  asm volatile("s_waitcnt vmcnt(3)\n\ts_barrier" ::: "memory");

  for (int kt = 0; kt < 32; ++kt) {
    const int cur = kt % 3;
    bf16x8 af[4], bfr[2];
#pragma unroll
    for (int i = 0; i < 4; ++i)
      af[i] = *(const bf16x8*)&lQ[cur][(i * 16 + lr) * 32 + lk];
#pragma unroll
    for (int j = 0; j < 2; ++j)
      bfr[j] = *(const bf16x8*)&lK[cur][(w * 32 + j * 16 + lr) * 32 + lk];

    const int tp = (kt + 2 < 32) ? kt + 2 : kt;  // dummy tail
    stageQK((kt + 2) % 3, tp * 32);

#pragma unroll
    for (int i = 0; i < 4; ++i)
#pragma unroll
      for (int j = 0; j < 2; ++j)
        sc[i][j] = mfma16(af[i], bfr[j], sc[i][j]);

    asm volatile("s_waitcnt vmcnt(3)\n\ts_barrier" ::: "memory");
  }

  // ---- decay-mask epilogue -> P bf16 in LDS; V ring prologue overlapped ----
  const int er = (l >> 4) * 4, ec = l & 15;
#pragma unroll
  for (int i = 0; i < 4; ++i)
#pragma unroll
    for (int j = 0; j < 2; ++j)
#pragma unroll
      for (int r = 0; r < 4; ++r) {
        int tl = i * 16 + er + r;
        int sl = w * 32 + j * 16 + ec;
        int sg = T0 - 64 + sl;
        int delta = (T0 + tl) - 1 - sg;
        float wgt = (delta >= 0 && delta < 64 && sg >= 0)
                        ? exp2f((float)delta * l2d) : 0.f;
        lP[tl * 136 + sl] = (bf16)(sc[i][j][r] * wgt);
      }

  auto stageV = [&](int buf, int g) {
    int nc = g >> 2, ks = g & 3;
#pragma unroll
    for (int cc = 0; cc < 2; ++cc) {
      int c = 2 * w + cc;
      int drow = nc * 128 + c * 16 + (l >> 2);
      int scol = T0 - 64 + ks * 32 + (l & 3) * 8;
      if (scol < 0) scol = 0;
      const bf16* gv = Vt + ((size_t)b * ADIM + drow) * ASEQ + scol;
      gload_lds16(gv, &lV[buf][c * 16 * 32]);
    }
  };

  stageV(0, 0);
  stageV(1, 1);
  // retires QK-tail dummies + V0; V1 in flight; lP writes visible after barrier
  asm volatile("s_waitcnt vmcnt(2) lgkmcnt(0)\n\ts_barrier" ::: "memory");

  // ---- phase 2: out = P V, 3-slot ring ----
  f32x4 o[4][2] = {};
  for (int g = 0; g < 32; ++g) {
    const int cur = g % 3;
    const int nc = g >> 2, ks = g & 3;
    bf16x8 af[4], bfr[2];
#pragma unroll
    for (int i = 0; i < 4; ++i)
      af[i] = *(const bf16x8*)&lP[(i * 16 + lr) * 136 + ks * 32 + lk];
#pragma unroll
    for (int j = 0; j < 2; ++j)
      bfr[j] = *(const bf16x8*)&lV[cur][(w * 32 + j * 16 + lr) * 32 + lk];

    const int gp = (g + 2 < 32) ? g + 2 : g;     // dummy tail
    stageV((g + 2) % 3, gp);

#pragma unroll
    for (int i = 0; i < 4; ++i)
#pragma unroll
      for (int j = 0; j < 2; ++j)
        o[i][j] = mfma16(af[i], bfr[j], o[i][j]);

    if (ks == 3) {
#pragma unroll
      for (int i = 0; i < 4; ++i)
#pragma unroll
        for (int j = 0; j < 2; ++j) {
#pragma unroll
          for (int r = 0; r < 4; ++r) {
            int tl = i * 16 + er + r;
            int dl = nc * 128 + w * 32 + j * 16 + ec;
            Rb[(size_t)(b * ASEQ + T0 + tl) * ADIM + dl] = (bf16)o[i][j][r];
          }
#pragma unroll
          for (int r = 0; r < 4; ++r) o[i][j][r] = 0.f;
        }
    }
    asm volatile("s_waitcnt vmcnt(2)\n\ts_barrier" ::: "memory");
  }
  asm volatile("s_waitcnt vmcnt(0)" ::: "memory");  // drain dummies before endpgm
}

extern "C" void kernel_launch(void* const* d_in, const int* in_sizes, int n_in,
                              void* d_out, int out_size, void* d_ws, size_t ws_size,
                              hipStream_t stream) {
  const float* x  = (const float*)d_in[0];
  const float* Wq = (const float*)d_in[1];
  const float* bq = (const float*)d_in[2];
  const float* Wk = (const float*)d_in[3];
  const float* bk = (const float*)d_in[4];
  const float* Wv = (const float*)d_in[5];
  const float* bv = (const float*)d_in[6];
  const float* Wo = (const float*)d_in[7];
  const float* bo = (const float*)d_in[8];
  const float* dp = (const float*)d_in[9];
  float* out = (float*)d_out;

  char* ws = (char*)d_ws;
  signed char* Xq  = (signed char*)(ws + ((size_t)0 << 20));   // 16 MB
  float*       sx  = (float*)(ws + ((size_t)16 << 20));        // 64 KB
  signed char* WcQ = (signed char*)(ws + ((size_t)17 << 20));  // 3 MB
  float*       swc = (float*)(ws + ((size_t)20 << 20));        // 12 KB
  bf16* Qb  = (bf16*)(ws + ((size_t)32 << 20));
  bf16* Kb  = (bf16*)(ws + ((size_t)64 << 20));
  bf16* Vtb = (bf16*)(ws + ((size_t)96 << 20));                // [8][1024][2048]
  bf16* Rbb = (bf16*)(ws + ((size_t)128 << 20));
  bf16* WcT = (bf16*)(ws + ((size_t)160 << 20));               // [3072][1024] bf16
  bf16* WoT = (bf16*)(ws + ((size_t)166 << 20));               // [1024][1024] bf16

  k_prep_w<<<1024, 256, 0, stream>>>(Wq, Wk, Wv, Wo, WcT, WoT);
  k_q<<<4864, 256, 0, stream>>>(x, WcT, Xq, sx, WcQ, swc);
  k_qkv8<<<768, 512, 0, stream>>>(
      Xq, WcQ, sx, swc, bq, bk, bv, Qb, Kb, Vtb);
  k_attn<<<dim3(32, 8), 256, 0, stream>>>(Qb, Kb, Vtb, Rbb, dp);
  k_gout<<<256, 512, 0, stream>>>(Rbb, WoT, bo, out);
}

// Round 15
// 176.205 us; speedup vs baseline: 1.5577x; 1.0359x over previous
//
#include <hip/hip_runtime.h>
#include <cstdint>
#include <cstddef>

typedef __bf16 bf16;
typedef __attribute__((ext_vector_type(8))) __bf16 bf16x8;
typedef __attribute__((ext_vector_type(4))) __bf16 bf16x4;
typedef __attribute__((ext_vector_type(4))) float f32x4;
typedef __attribute__((ext_vector_type(4))) int i32x4;

#define ADIM 1024
#define ASEQ 2048
#define ABATCH 8

__device__ __forceinline__ void gload_lds16(const void* g, void* l) {
  __builtin_amdgcn_global_load_lds(
      (const __attribute__((address_space(1))) void*)g,
      (__attribute__((address_space(3))) void*)l,
      16, 0, 0);
}

__device__ __forceinline__ f32x4 mfma16(bf16x8 a, bf16x8 b, f32x4 c) {
  return __builtin_amdgcn_mfma_f32_16x16x32_bf16(a, b, c, 0, 0, 0);
}
__device__ __forceinline__ i32x4 mfma8i(i32x4 a, i32x4 b, i32x4 c) {
  return __builtin_amdgcn_mfma_i32_16x16x64_i8(a, b, c, 0, 0, 0);
}

// ------- prep: transpose weights to B^T bf16 (coalesced both sides) -------
__global__ __launch_bounds__(256) void k_prep_w(
    const float* __restrict__ Wq, const float* __restrict__ Wk,
    const float* __restrict__ Wv, const float* __restrict__ Wo,
    bf16* __restrict__ WcT, bf16* __restrict__ WoT) {
  const int b = blockIdx.x;
  const int which = b >> 8, t = b & 255;
  const int n0 = (t & 15) * 64, k0 = (t >> 4) * 64;
  const float* W = (which == 0) ? Wq : (which == 1) ? Wk : (which == 2) ? Wv : Wo;
  bf16* out = (which < 3) ? (WcT + (size_t)which * ADIM * ADIM) : WoT;

  __shared__ float tile[64][69];
  const int r = threadIdx.x >> 4, c4 = (threadIdx.x & 15) * 4;
#pragma unroll
  for (int p = 0; p < 4; ++p) {
    float4 f = *(const float4*)&W[(size_t)(k0 + p * 16 + r) * ADIM + n0 + c4];
    tile[p * 16 + r][c4 + 0] = f.x;
    tile[p * 16 + r][c4 + 1] = f.y;
    tile[p * 16 + r][c4 + 2] = f.z;
    tile[p * 16 + r][c4 + 3] = f.w;
  }
  __syncthreads();
#pragma unroll
  for (int p = 0; p < 4; ++p) {
    const int nn = p * 16 + r;
    bf16x4 o;
#pragma unroll
    for (int j = 0; j < 4; ++j) o[j] = (bf16)tile[c4 + j][nn];
    *(bf16x4*)&out[(size_t)(n0 + nn) * ADIM + k0 + c4] = o;
  }
}

// ---- quantize rows to i8 + per-row scale. One 64-lane wave per row. ----
// rows [0,16384): x f32 -> Xq,sx ; [16384,19456): WcT -> WcQ,swc ;
// [19456,20480): WoT -> WoQ,swo.
__global__ __launch_bounds__(256) void k_q(
    const float* __restrict__ x, const bf16* __restrict__ WcT,
    const bf16* __restrict__ WoT,
    signed char* __restrict__ Xq, float* __restrict__ sx,
    signed char* __restrict__ WcQ, float* __restrict__ swc,
    signed char* __restrict__ WoQ, float* __restrict__ swo) {
  const int row = blockIdx.x * 4 + (threadIdx.x >> 6);
  const int l = threadIdx.x & 63;
  float v[16];
  if (row < 16384) {
    const float4* p = (const float4*)&x[(size_t)row * ADIM + l * 16];
#pragma unroll
    for (int g = 0; g < 4; ++g) {
      float4 f = p[g];
      v[g * 4 + 0] = f.x; v[g * 4 + 1] = f.y; v[g * 4 + 2] = f.z; v[g * 4 + 3] = f.w;
    }
  } else {
    const bf16* src = (row < 19456)
        ? (WcT + (size_t)(row - 16384) * ADIM)
        : (WoT + (size_t)(row - 19456) * ADIM);
    const bf16x8* p = (const bf16x8*)&src[l * 16];
#pragma unroll
    for (int g = 0; g < 2; ++g) {
      bf16x8 f = p[g];
#pragma unroll
      for (int e = 0; e < 8; ++e) v[g * 8 + e] = (float)f[e];
    }
  }
  float m = 0.f;
#pragma unroll
  for (int e = 0; e < 16; ++e) m = fmaxf(m, fabsf(v[e]));
#pragma unroll
  for (int off = 32; off >= 1; off >>= 1) m = fmaxf(m, __shfl_xor(m, off));
  m = fmaxf(m, 1e-20f);
  const float inv = 127.f / m;
  i32x4 pk;
#pragma unroll
  for (int g = 0; g < 4; ++g) {
    int word = 0;
#pragma unroll
    for (int e = 0; e < 4; ++e) {
      int q = __float2int_rn(v[g * 4 + e] * inv);
      q = max(-127, min(127, q));
      word |= (q & 255) << (e * 8);
    }
    pk[g] = word;
  }
  if (row < 16384) {
    *(i32x4*)&Xq[(size_t)row * ADIM + l * 16] = pk;
    if (l == 0) sx[row] = m / 127.f;
  } else if (row < 19456) {
    *(i32x4*)&WcQ[(size_t)(row - 16384) * ADIM + l * 16] = pk;
    if (l == 0) swc[row - 16384] = m / 127.f;
  } else {
    *(i32x4*)&WoQ[(size_t)(row - 19456) * ADIM + l * 16] = pk;
    if (l == 0) swo[row - 19456] = m / 127.f;
  }
}

// ---- quantize R (attn output, bf16) rows -> Rq i8 + sxr ----
__global__ __launch_bounds__(256) void k_qr(
    const bf16* __restrict__ Rb, signed char* __restrict__ Rq,
    float* __restrict__ sxr) {
  const int row = blockIdx.x * 4 + (threadIdx.x >> 6);
  const int l = threadIdx.x & 63;
  float v[16];
  const bf16x8* p = (const bf16x8*)&Rb[(size_t)row * ADIM + l * 16];
#pragma unroll
  for (int g = 0; g < 2; ++g) {
    bf16x8 f = p[g];
#pragma unroll
    for (int e = 0; e < 8; ++e) v[g * 8 + e] = (float)f[e];
  }
  float m = 0.f;
#pragma unroll
  for (int e = 0; e < 16; ++e) m = fmaxf(m, fabsf(v[e]));
#pragma unroll
  for (int off = 32; off >= 1; off >>= 1) m = fmaxf(m, __shfl_xor(m, off));
  m = fmaxf(m, 1e-20f);
  const float inv = 127.f / m;
  i32x4 pk;
#pragma unroll
  for (int g = 0; g < 4; ++g) {
    int word = 0;
#pragma unroll
    for (int e = 0; e < 4; ++e) {
      int q = __float2int_rn(v[g * 4 + e] * inv);
      q = max(-127, min(127, q));
      word |= (q & 255) << (e * 8);
    }
    pk[g] = word;
  }
  *(i32x4*)&Rq[(size_t)row * ADIM + l * 16] = pk;
  if (l == 0) sxr[row] = m / 127.f;
}

// ====== i8 GEMM core: 256x256 tile, BK=128B dbuf, 1 fence/step (r13-proven) ======
// MODE 0: QKV dequant epilogue -> Q/K/Vt bf16. MODE 1: out fp32 = deq + bias0.
template<int MODE>
__global__ __launch_bounds__(512, 2) void k_gi8(
    const signed char* __restrict__ A, const signed char* __restrict__ BT,
    const float* __restrict__ sa, const float* __restrict__ sb,
    const float* __restrict__ bias0, const float* __restrict__ bias1,
    const float* __restrict__ bias2,
    bf16* __restrict__ Qo, bf16* __restrict__ Ko, bf16* __restrict__ Vto,
    float* __restrict__ outF, int ntn)
{
  constexpr int K = 1024;           // bytes per row
  constexpr int KT = 8;             // steps of BK=128 bytes
  const int nwg = gridDim.x;
  const int cpx = nwg >> 3;
  const int flat = blockIdx.x;
  const int sw = (flat & 7) * cpx + (flat >> 3);
  const int bx = sw % ntn, by = sw / ntn;
  const int m0 = by * 256, n0 = bx * 256;

  const int tid = threadIdx.x;
  const int l = tid & 63, w = tid >> 6;
  const int wm = w >> 2, wn = w & 3;
  const int lr = l & 15, kg = l >> 4;

  __shared__ alignas(16) signed char sA[2][256 * 128];   // 64 KiB
  __shared__ alignas(16) signed char sB[2][256 * 128];   // 64 KiB

  i32x4 acc[8][4] = {};

  int oA[8], oB[4];
#pragma unroll
  for (int i = 0; i < 8; ++i) {
    int r = wm * 128 + i * 16 + lr;
    oA[i] = (r * 8 + (kg ^ (r & 7))) * 16;
  }
#pragma unroll
  for (int j = 0; j < 4; ++j) {
    int r = wn * 64 + j * 16 + lr;
    oB[j] = (r * 8 + (kg ^ (r & 7))) * 16;
  }

  auto stA = [&](int c, int kt, int chunk) {
    int s = chunk * 512 + tid;
    int prow = s >> 3, ps = s & 7;
    int lc = ps ^ (prow & 7);
    gload_lds16(A + (size_t)(m0 + prow) * K + kt * 128 + lc * 16,
                &sA[c][(size_t)s * 16]);
  };
  auto stB = [&](int c, int kt, int chunk) {
    int s = chunk * 512 + tid;
    int prow = s >> 3, ps = s & 7;
    int lc = ps ^ (prow & 7);
    gload_lds16(BT + (size_t)(n0 + prow) * K + kt * 128 + lc * 16,
                &sB[c][(size_t)s * 16]);
  };

#pragma unroll
  for (int ch = 0; ch < 4; ++ch) { stA(0, 0, ch); stB(0, 0, ch); }
  asm volatile("s_waitcnt vmcnt(0)\n\ts_barrier" ::: "memory");

  for (int t = 0; t < KT; ++t) {
    const int c = t & 1;
    const char* bA = (const char*)&sA[c][0];
    const char* bB = (const char*)&sB[c][0];

    i32x4 af[8], bfr[4];
#pragma unroll
    for (int i = 0; i < 8; ++i) af[i] = *(const i32x4*)(bA + oA[i]);
#pragma unroll
    for (int j = 0; j < 4; ++j) bfr[j] = *(const i32x4*)(bB + oB[j]);

    if (t + 1 < KT) {
#pragma unroll
      for (int ch = 0; ch < 4; ++ch) { stA(c ^ 1, t + 1, ch); stB(c ^ 1, t + 1, ch); }
    }

    __builtin_amdgcn_s_setprio(1);
#pragma unroll
    for (int i = 0; i < 8; ++i)
#pragma unroll
      for (int j = 0; j < 4; ++j)
        acc[i][j] = mfma8i(af[i], bfr[j], acc[i][j]);
    __builtin_amdgcn_s_setprio(0);

#pragma unroll
    for (int i = 0; i < 8; ++i) af[i] = *(const i32x4*)(bA + (oA[i] ^ 64));
#pragma unroll
    for (int j = 0; j < 4; ++j) bfr[j] = *(const i32x4*)(bB + (oB[j] ^ 64));

    __builtin_amdgcn_s_setprio(1);
#pragma unroll
    for (int i = 0; i < 8; ++i)
#pragma unroll
      for (int j = 0; j < 4; ++j)
        acc[i][j] = mfma8i(af[i], bfr[j], acc[i][j]);
    __builtin_amdgcn_s_setprio(0);

    asm volatile("s_waitcnt vmcnt(0)\n\ts_barrier" ::: "memory");
  }

  // ---- dequant epilogue ----
  const int cb = n0 >> 10;
#pragma unroll
  for (int i = 0; i < 8; ++i) {
#pragma unroll
    for (int jj = 0; jj < 4; ++jj) {
      const int n = n0 + wn * 64 + jj * 16 + lr;
      const int m0r = m0 + wm * 128 + i * 16 + kg * 4;
      const float sbn = sb[n];
      const float4 s4 = *(const float4*)&sa[m0r];
      float de[4];
      de[0] = (float)acc[i][jj][0] * s4.x * sbn;
      de[1] = (float)acc[i][jj][1] * s4.y * sbn;
      de[2] = (float)acc[i][jj][2] * s4.z * sbn;
      de[3] = (float)acc[i][jj][3] * s4.w * sbn;
      if (MODE == 0) {
        const int nn = n & 1023;
        if (cb == 0) {
          const float b_ = bias0[nn];
#pragma unroll
          for (int r = 0; r < 4; ++r)
            Qo[(size_t)(m0r + r) * ADIM + nn] = (bf16)(de[r] + b_);
        } else if (cb == 1) {
          const float b_ = bias1[nn];
#pragma unroll
          for (int r = 0; r < 4; ++r) {
            float v = de[r] + b_;
            Ko[(size_t)(m0r + r) * ADIM + nn] = (bf16)(v > 0.f ? v + 1.f : __expf(v));
          }
        } else {
          const float b_ = bias2[nn];
          const int bb = m0r >> 11, t0c = m0r & 2047;
          bf16x4 pk;
#pragma unroll
          for (int r = 0; r < 4; ++r) pk[r] = (bf16)(de[r] + b_);
          *(bf16x4*)&Vto[((size_t)bb * ADIM + nn) * ASEQ + t0c] = pk;
        }
      } else {
        const float b_ = bias0[n];
#pragma unroll
        for (int r = 0; r < 4; ++r)
          outF[(size_t)(m0r + r) * ADIM + n] = de[r] + b_;
      }
    }
  }
}

// ------ windowed decay attention, 3-slot counted-vmcnt rings (r14-proven) ------
__global__ __launch_bounds__(256) void k_attn(
    const bf16* __restrict__ Qg, const bf16* __restrict__ Kg,
    const bf16* __restrict__ Vt, bf16* __restrict__ Rb,
    const float* __restrict__ decay_param)
{
  const int b = blockIdx.y;
  const int T0 = blockIdx.x * 64;
  const int tid = threadIdx.x;
  const int l = tid & 63, w = tid >> 6;
  const int lr = l & 15, lk = (l >> 4) * 8;

  const float dp = decay_param[0];
  const float decay = 1.f / (1.f + __expf(-dp));
  const float l2d = __log2f(decay);

  __shared__ alignas(16) bf16 lQ[3][64 * 32];
  __shared__ alignas(16) bf16 lK[3][128 * 32];
  __shared__ alignas(16) bf16 lV[3][128 * 32];
  __shared__ alignas(16) bf16 lP[64 * 136];

  const bf16* Qb = Qg + (size_t)(b * ASEQ + T0) * ADIM;

  auto stageQK = [&](int buf, int k0) {
    {
      const bf16* g = Qb + (size_t)(w * 16 + (l >> 2)) * ADIM + k0 + (l & 3) * 8;
      gload_lds16(g, &lQ[buf][w * 16 * 32]);
    }
#pragma unroll
    for (int cc = 0; cc < 2; ++cc) {
      int c = 2 * w + cc;
      int sg = T0 - 64 + c * 16 + (l >> 2);
      if (sg < 0) sg = 0;
      const bf16* g = Kg + (size_t)(b * ASEQ + sg) * ADIM + k0 + (l & 3) * 8;
      gload_lds16(g, &lK[buf][c * 16 * 32]);
    }
  };

  f32x4 sc[4][2] = {};
  stageQK(0, 0);
  stageQK(1, 32);
  asm volatile("s_waitcnt vmcnt(3)\n\ts_barrier" ::: "memory");

  for (int kt = 0; kt < 32; ++kt) {
    const int cur = kt % 3;
    bf16x8 af[4], bfr[2];
#pragma unroll
    for (int i = 0; i < 4; ++i)
      af[i] = *(const bf16x8*)&lQ[cur][(i * 16 + lr) * 32 + lk];
#pragma unroll
    for (int j = 0; j < 2; ++j)
      bfr[j] = *(const bf16x8*)&lK[cur][(w * 32 + j * 16 + lr) * 32 + lk];

    const int tp = (kt + 2 < 32) ? kt + 2 : kt;
    stageQK((kt + 2) % 3, tp * 32);

#pragma unroll
    for (int i = 0; i < 4; ++i)
#pragma unroll
      for (int j = 0; j < 2; ++j)
        sc[i][j] = mfma16(af[i], bfr[j], sc[i][j]);

    asm volatile("s_waitcnt vmcnt(3)\n\ts_barrier" ::: "memory");
  }

  const int er = (l >> 4) * 4, ec = l & 15;
#pragma unroll
  for (int i = 0; i < 4; ++i)
#pragma unroll
    for (int j = 0; j < 2; ++j)
#pragma unroll
      for (int r = 0; r < 4; ++r) {
        int tl = i * 16 + er + r;
        int sl = w * 32 + j * 16 + ec;
        int sg = T0 - 64 + sl;
        int delta = (T0 + tl) - 1 - sg;
        float wgt = (delta >= 0 && delta < 64 && sg >= 0)
                        ? exp2f((float)delta * l2d) : 0.f;
        lP[tl * 136 + sl] = (bf16)(sc[i][j][r] * wgt);
      }

  auto stageV = [&](int buf, int g) {
    int nc = g >> 2, ks = g & 3;
#pragma unroll
    for (int cc = 0; cc < 2; ++cc) {
      int c = 2 * w + cc;
      int drow = nc * 128 + c * 16 + (l >> 2);
      int scol = T0 - 64 + ks * 32 + (l & 3) * 8;
      if (scol < 0) scol = 0;
      const bf16* gv = Vt + ((size_t)b * ADIM + drow) * ASEQ + scol;
      gload_lds16(gv, &lV[buf][c * 16 * 32]);
    }
  };

  stageV(0, 0);
  stageV(1, 1);
  asm volatile("s_waitcnt vmcnt(2) lgkmcnt(0)\n\ts_barrier" ::: "memory");

  f32x4 o[4][2] = {};
  for (int g = 0; g < 32; ++g) {
    const int cur = g % 3;
    const int nc = g >> 2, ks = g & 3;
    bf16x8 af[4], bfr[2];
#pragma unroll
    for (int i = 0; i < 4; ++i)
      af[i] = *(const bf16x8*)&lP[(i * 16 + lr) * 136 + ks * 32 + lk];
#pragma unroll
    for (int j = 0; j < 2; ++j)
      bfr[j] = *(const bf16x8*)&lV[cur][(w * 32 + j * 16 + lr) * 32 + lk];

    const int gp = (g + 2 < 32) ? g + 2 : g;
    stageV((g + 2) % 3, gp);

#pragma unroll
    for (int i = 0; i < 4; ++i)
#pragma unroll
      for (int j = 0; j < 2; ++j)
        o[i][j] = mfma16(af[i], bfr[j], o[i][j]);

    if (ks == 3) {
#pragma unroll
      for (int i = 0; i < 4; ++i)
#pragma unroll
        for (int j = 0; j < 2; ++j) {
#pragma unroll
          for (int r = 0; r < 4; ++r) {
            int tl = i * 16 + er + r;
            int dl = nc * 128 + w * 32 + j * 16 + ec;
            Rb[(size_t)(b * ASEQ + T0 + tl) * ADIM + dl] = (bf16)o[i][j][r];
          }
#pragma unroll
          for (int r = 0; r < 4; ++r) o[i][j][r] = 0.f;
        }
    }
    asm volatile("s_waitcnt vmcnt(2)\n\ts_barrier" ::: "memory");
  }
  asm volatile("s_waitcnt vmcnt(0)" ::: "memory");
}

extern "C" void kernel_launch(void* const* d_in, const int* in_sizes, int n_in,
                              void* d_out, int out_size, void* d_ws, size_t ws_size,
                              hipStream_t stream) {
  const float* x  = (const float*)d_in[0];
  const float* Wq = (const float*)d_in[1];
  const float* bq = (const float*)d_in[2];
  const float* Wk = (const float*)d_in[3];
  const float* bk = (const float*)d_in[4];
  const float* Wv = (const float*)d_in[5];
  const float* bv = (const float*)d_in[6];
  const float* Wo = (const float*)d_in[7];
  const float* bo = (const float*)d_in[8];
  const float* dp = (const float*)d_in[9];
  float* out = (float*)d_out;

  char* ws = (char*)d_ws;
  // Xq/Rq and sx/sxr alias (Xq,sx dead after qkv8; Rq,sxr written after attn)
  signed char* Xq  = (signed char*)(ws + ((size_t)0 << 20));   // 16 MB
  signed char* Rq  = Xq;
  float*       sx  = (float*)(ws + ((size_t)16 << 20));        // 64 KB
  float*       sxr = sx;
  signed char* WcQ = (signed char*)(ws + ((size_t)17 << 20));  // 3 MB
  float*       swc = (float*)(ws + ((size_t)20 << 20));        // 12 KB
  signed char* WoQ = (signed char*)(ws + ((size_t)21 << 20));  // 1 MB
  float*       swo = (float*)(ws + ((size_t)22 << 20));        // 4 KB
  bf16* Qb  = (bf16*)(ws + ((size_t)32 << 20));
  bf16* Kb  = (bf16*)(ws + ((size_t)64 << 20));
  bf16* Vtb = (bf16*)(ws + ((size_t)96 << 20));                // [8][1024][2048]
  bf16* Rbb = (bf16*)(ws + ((size_t)128 << 20));
  bf16* WcT = (bf16*)(ws + ((size_t)160 << 20));               // [3072][1024] bf16
  bf16* WoT = (bf16*)(ws + ((size_t)166 << 20));               // [1024][1024] bf16

  k_prep_w<<<1024, 256, 0, stream>>>(Wq, Wk, Wv, Wo, WcT, WoT);
  k_q<<<5120, 256, 0, stream>>>(x, WcT, WoT, Xq, sx, WcQ, swc, WoQ, swo);
  k_gi8<0><<<768, 512, 0, stream>>>(
      Xq, WcQ, sx, swc, bq, bk, bv, Qb, Kb, Vtb, nullptr, 12);
  k_attn<<<dim3(32, 8), 256, 0, stream>>>(Qb, Kb, Vtb, Rbb, dp);
  k_qr<<<4096, 256, 0, stream>>>(Rbb, Rq, sxr);
  k_gi8<1><<<256, 512, 0, stream>>>(
      Rq, WoQ, sxr, swo, bo, nullptr, nullptr, nullptr, nullptr, nullptr, out, 4);
}